// Round 1
// baseline (5676.595 us; speedup 1.0000x reference)
//
#include <hip/hip_runtime.h>

#define HW 4096   // 64*64

// ---------------------------------------------------------------------------
// Generic 3x3 conv, stride 1, pad 1, on 64x64 images, B=1.
// Block: 256 threads. Spatial tile 16x16. Each thread: 2x2 pixels x J couts.
// COT = 4*J couts per block. Input staged in LDS in CIN_CHUNK=4 channel chunks
// (18x18 halo tile). Supports a channel-concatenated input via (inA,inB,splitA).
// ---------------------------------------------------------------------------
template<int J>
__global__ __launch_bounds__(256)
void conv3x3_k(const float* __restrict__ inA, const float* __restrict__ inB,
               int splitA, int Cin, int Cout,
               const float* __restrict__ wgt, float* __restrict__ out, int relu)
{
    constexpr int COT = 4 * J;
    constexpr int CC  = 4;                 // input channels per chunk
    __shared__ float s_in[CC][18 * 18];
    __shared__ float s_w[COT][CC][9];

    const int tid = threadIdx.x;
    const int bx  = blockIdx.x;            // 0..15 spatial tile
    const int ty0 = (bx >> 2) * 16, tx0 = (bx & 3) * 16;
    const int co_base = blockIdx.y * COT;

    const int pxg = tid & 63;              // 64 pixel groups (2x2 each)
    const int gy  = pxg >> 3, gx = pxg & 7;
    const int cog = tid >> 6;              // 0..3 cout groups (wave-uniform)

    float acc[J][4];
#pragma unroll
    for (int j = 0; j < J; ++j)
#pragma unroll
        for (int p = 0; p < 4; ++p) acc[j][p] = 0.f;

    for (int cb = 0; cb < Cin; cb += CC) {
        // ---- stage input chunk (CC x 18x18, zero-padded halo) ----
        for (int i = tid; i < CC * 324; i += 256) {
            int c  = i / 324;
            int r  = (i % 324) / 18;
            int cc = i % 18;
            int gyg = ty0 - 1 + r, gxg = tx0 - 1 + cc;
            float v = 0.f;
            if (gyg >= 0 && gyg < 64 && gxg >= 0 && gxg < 64) {
                int ch = cb + c;
                v = (ch < splitA) ? inA[(size_t)ch * HW + gyg * 64 + gxg]
                                  : inB[(size_t)(ch - splitA) * HW + gyg * 64 + gxg];
            }
            s_in[c][r * 18 + cc] = v;
        }
        // ---- stage weights (COT x CC x 9) ----
        for (int i = tid; i < COT * CC * 9; i += 256) {
            int col = i / (CC * 9);
            int c   = (i / 9) % CC;
            int k   = i % 9;
            int co  = co_base + col;
            s_w[col][c][k] = (co < Cout) ? wgt[((size_t)co * Cin + cb + c) * 9 + k] : 0.f;
        }
        __syncthreads();

#pragma unroll
        for (int c = 0; c < CC; ++c) {
            float win[4][4];
#pragma unroll
            for (int r = 0; r < 4; ++r)
#pragma unroll
                for (int q = 0; q < 4; ++q)
                    win[r][q] = s_in[c][(gy * 2 + r) * 18 + gx * 2 + q];
#pragma unroll
            for (int j = 0; j < J; ++j) {
#pragma unroll
                for (int ky = 0; ky < 3; ++ky)
#pragma unroll
                    for (int kx = 0; kx < 3; ++kx) {
                        float wv = s_w[cog * J + j][c][ky * 3 + kx];
                        acc[j][0] += win[ky][kx]         * wv;
                        acc[j][1] += win[ky][kx + 1]     * wv;
                        acc[j][2] += win[ky + 1][kx]     * wv;
                        acc[j][3] += win[ky + 1][kx + 1] * wv;
                    }
            }
        }
        __syncthreads();
    }

    const int py = ty0 + gy * 2, px = tx0 + gx * 2;
#pragma unroll
    for (int j = 0; j < J; ++j) {
        int co = co_base + cog * J + j;
        if (co < Cout) {
#pragma unroll
            for (int p = 0; p < 4; ++p) {
                float v = acc[j][p];
                if (relu) v = fmaxf(v, 0.f);
                out[(size_t)co * HW + (py + (p >> 1)) * 64 + px + (p & 1)] = v;
            }
        }
    }
}

// ---------------------------------------------------------------------------
// Deformable conv: X [768][4096] (reference features), OF [18][4096] offsets
// (channel 2t = dy, 2t+1 = dx for tap t = ki*3+kj), Wt [768][6912] weights
// (k = c*9 + tap), out [768][4096].
// Grid: (64 rows, 6 cout tiles of 128). Block 256.
// Per-pixel bilinear meta (4 corner idx + 4 weights for 9 taps x 64 px) is
// computed once into LDS. K-loop: 384 chunks of 18 (2 channels x 9 taps):
// gather sampled values into LDS, then 128co x 64px register-tiled GEMM step.
// Thread: pxg = tid&15 -> 4 px; cog = tid>>4 -> 8 couts. acc[8][4].
// ---------------------------------------------------------------------------
__global__ __launch_bounds__(256)
void deform_k(const float* __restrict__ X, const float* __restrict__ OF,
              const float* __restrict__ Wt, float* __restrict__ out)
{
    __shared__ int   s_idx[4][9][64];
    __shared__ float s_bw[4][9][64];
    __shared__ float s_s[18 * 64];
    __shared__ float s_w[18 * 132];   // row stride 132 (16B-aligned rows, de-conflicted)

    const int tid = threadIdx.x;
    const int row = blockIdx.x;       // 0..63
    const int cot = blockIdx.y;       // 0..5

    // ---- bilinear meta: 9 taps x 64 px ----
    for (int t = tid; t < 9 * 64; t += 256) {
        int kk = t >> 6, x = t & 63;
        float dy = OF[(size_t)(2 * kk) * HW + row * 64 + x];
        float dx = OF[(size_t)(2 * kk + 1) * HW + row * 64 + x];
        float py  = (float)(row - 1 + kk / 3) + dy;
        float pxf = (float)(x   - 1 + kk % 3) + dx;
        // clamp to keep int conversion safe; does not change validity outcomes
        py  = fminf(fmaxf(py,  -1e6f), 1e6f);
        pxf = fminf(fmaxf(pxf, -1e6f), 1e6f);
        float y0f = floorf(py), x0f = floorf(pxf);
        float wy1 = py - y0f, wx1 = pxf - x0f;
        float wy0 = 1.f - wy1, wx0 = 1.f - wx1;
        bool vy0 = (y0f >= 0.f)       && (y0f <= 63.f);
        bool vy1 = (y0f + 1.f >= 0.f) && (y0f + 1.f <= 63.f);
        bool vx0 = (x0f >= 0.f)       && (x0f <= 63.f);
        bool vx1 = (x0f + 1.f >= 0.f) && (x0f + 1.f <= 63.f);
        int y0 = (int)fminf(fmaxf(y0f,       0.f), 63.f);
        int y1 = (int)fminf(fmaxf(y0f + 1.f, 0.f), 63.f);
        int x0 = (int)fminf(fmaxf(x0f,       0.f), 63.f);
        int x1 = (int)fminf(fmaxf(x0f + 1.f, 0.f), 63.f);
        s_idx[0][kk][x] = y0 * 64 + x0;  s_bw[0][kk][x] = (vy0 && vx0) ? wy0 * wx0 : 0.f;
        s_idx[1][kk][x] = y0 * 64 + x1;  s_bw[1][kk][x] = (vy0 && vx1) ? wy0 * wx1 : 0.f;
        s_idx[2][kk][x] = y1 * 64 + x0;  s_bw[2][kk][x] = (vy1 && vx0) ? wy1 * wx0 : 0.f;
        s_idx[3][kk][x] = y1 * 64 + x1;  s_bw[3][kk][x] = (vy1 && vx1) ? wy1 * wx1 : 0.f;
    }
    __syncthreads();

    const int pxg = tid & 15;     // 4 px each
    const int cog = tid >> 4;     // 8 couts each
    float acc[8][4];
#pragma unroll
    for (int j = 0; j < 8; ++j)
#pragma unroll
        for (int p = 0; p < 4; ++p) acc[j][p] = 0.f;

    for (int ch = 0; ch < 384; ++ch) {
        const int kb = ch * 18;
        // stage weights: 18 k x 128 co, stored transposed [kl][co]
        for (int i = tid; i < 18 * 128; i += 256) {
            int co = i / 18, kl = i % 18;
            s_w[kl * 132 + co] = Wt[(size_t)(cot * 128 + co) * 6912 + kb + kl];
        }
        // gather sampled values: 18 k x 64 px
        for (int i = tid; i < 18 * 64; i += 256) {
            int kl = i >> 6, x = i & 63;
            int c  = ch * 2 + (kl >= 9 ? 1 : 0);
            int kk = (kl >= 9) ? kl - 9 : kl;
            const float* Xc = X + (size_t)c * HW;
            float v = s_bw[0][kk][x] * Xc[s_idx[0][kk][x]]
                    + s_bw[1][kk][x] * Xc[s_idx[1][kk][x]]
                    + s_bw[2][kk][x] * Xc[s_idx[2][kk][x]]
                    + s_bw[3][kk][x] * Xc[s_idx[3][kk][x]];
            s_s[kl * 64 + x] = v;
        }
        __syncthreads();

#pragma unroll
        for (int kl = 0; kl < 18; ++kl) {
            float4 sv  = *(const float4*)&s_s[kl * 64 + pxg * 4];
            float4 wv0 = *(const float4*)&s_w[kl * 132 + cog * 8];
            float4 wv1 = *(const float4*)&s_w[kl * 132 + cog * 8 + 4];
            float wj[8] = {wv0.x, wv0.y, wv0.z, wv0.w, wv1.x, wv1.y, wv1.z, wv1.w};
            float sp[4] = {sv.x, sv.y, sv.z, sv.w};
#pragma unroll
            for (int j = 0; j < 8; ++j)
#pragma unroll
                for (int p = 0; p < 4; ++p)
                    acc[j][p] += wj[j] * sp[p];
        }
        __syncthreads();
    }

#pragma unroll
    for (int j = 0; j < 8; ++j) {
        int co = cot * 128 + cog * 8 + j;
        float4 v = make_float4(acc[j][0], acc[j][1], acc[j][2], acc[j][3]);
        *(float4*)&out[(size_t)co * HW + row * 64 + pxg * 4] = v;
    }
}

// ---------------------------------------------------------------------------
extern "C" void kernel_launch(void* const* d_in, const int* in_sizes, int n_in,
                              void* d_out, int out_size, void* d_ws, size_t ws_size,
                              hipStream_t stream) {
    const float* x_in  = (const float*)d_in[0];   // input_features   [768][4096]
    const float* x_ref = (const float*)d_in[1];   // reference_features [768][4096]
    const float* w1    = (const float*)d_in[2];   // [192][1536][9]
    const float* w2    = (const float*)d_in[3];   // [192][192][9]
    const float* w3    = (const float*)d_in[4];   // [1536][192][9]
    const float* ow    = (const float*)d_in[5];   // [18][1536][9]
    const float* dw    = (const float*)d_in[6];   // [768][768][9]
    float* out = (float*)d_out;                   // [768][4096]

    float* h1   = (float*)d_ws;                   // 192*4096
    float* h2   = h1  + 192 * HW;                 // 192*4096
    float* est  = h2  + 192 * HW;                 // 1536*4096
    float* offs = est + 1536 * HW;                // 18*4096
    // total ws use: ~31.8 MB

    const int BIG = 1 << 30;
    // conv1: concat(x_in, x_ref) 1536 -> 192, relu    (COT=8, grid 16x24)
    conv3x3_k<2><<<dim3(16, 24), 256, 0, stream>>>(x_in, x_ref, 768, 1536, 192, w1, h1, 1);
    // conv2: 192 -> 192, relu
    conv3x3_k<2><<<dim3(16, 24), 256, 0, stream>>>(h1, h1, BIG, 192, 192, w2, h2, 1);
    // conv3: 192 -> 1536                               (COT=16, grid 16x96)
    conv3x3_k<4><<<dim3(16, 96), 256, 0, stream>>>(h2, h2, BIG, 192, 1536, w3, est, 0);
    // conv4: 1536 -> 18 (offsets)                      (COT=8, grid 16x3)
    conv3x3_k<2><<<dim3(16, 3), 256, 0, stream>>>(est, est, BIG, 1536, 18, ow, offs, 0);
    // deformable conv
    deform_k<<<dim3(64, 6), 256, 0, stream>>>(x_ref, offs, dw, out);
}

// Round 2
// 505.385 us; speedup vs baseline: 11.2322x; 11.2322x over previous
//
#include <hip/hip_runtime.h>

#define HWPX 4096   // 64*64 pixels

typedef short s8v  __attribute__((ext_vector_type(8)));   // 8 x bf16 (4 VGPR)
typedef float f4v  __attribute__((ext_vector_type(4)));   // 4 x f32  (MFMA C/D)

__device__ inline unsigned short f2bf(float f) {          // RNE f32 -> bf16
    unsigned u = __float_as_uint(f);
    return (unsigned short)((u + 0x7fffu + ((u >> 16) & 1u)) >> 16);
}
__device__ inline float bf2f(unsigned s) {
    return __uint_as_float(s << 16);
}

// ---------------------------------------------------------------------------
// Transpose+concat+cast: x_in/x_ref [768][4096] f32 -> xcat [4096 px][1536 ch] bf16
// ---------------------------------------------------------------------------
__global__ __launch_bounds__(256)
void tr_cat_k(const float* __restrict__ xa, const float* __restrict__ xb,
              short* __restrict__ xt)
{
    __shared__ __align__(16) short T[64 * 72];
    const int c0 = blockIdx.x * 64, p0 = blockIdx.y * 64, tid = threadIdx.x;
    for (int i = tid; i < 4096; i += 256) {
        int cl = i >> 6, pl = i & 63;
        int c = c0 + cl;
        float v = (c < 768) ? xa[(size_t)c * HWPX + p0 + pl]
                            : xb[(size_t)(c - 768) * HWPX + p0 + pl];
        T[pl * 72 + cl] = (short)f2bf(v);
    }
    __syncthreads();
    for (int i = tid; i < 512; i += 256) {
        int pl = i >> 3, part = i & 7;
        uint4 v = *(const uint4*)&T[pl * 72 + part * 8];
        *(uint4*)&xt[(size_t)(p0 + pl) * 1536 + c0 + part * 8] = v;
    }
}

// ---------------------------------------------------------------------------
// Weight transform: src [Cout][Cin][9] f32 -> dst[co][K] bf16 with
// k = cb*288 + t*32 + cl   (cb = channel chunk of 32, t = tap, cl = ch-in-chunk)
// ---------------------------------------------------------------------------
__global__ __launch_bounds__(256)
void wprep_k(const float* __restrict__ src, short* __restrict__ dst,
             int Cin, int total)
{
    int i = blockIdx.x * 256 + threadIdx.x;
    if (i >= total) return;
    int K = Cin * 9;
    int co = i / K, r = i % K;
    int cb = r / 288, q = r % 288;
    int t = q >> 5, cl = q & 31;
    dst[i] = (short)f2bf(src[((size_t)co * Cin + cb * 32 + cl) * 9 + t]);
}

// ---------------------------------------------------------------------------
// Implicit-GEMM 3x3 conv via MFMA bf16. Tile: MT=64 couts x NT=128 px (2 rows).
// 4 waves, each 64m x 32n: per K-step(32) 4 A-frags + 2 B-frags + 8 MFMA.
// Input Xt pixel-major [4096][CinStr] bf16. K ordered (chunk32, tap, ch).
// mode 0: f32 partials [split][4096][Cstr] (K-split) ; mode 1: bf16 [4096][Cstr].
// ---------------------------------------------------------------------------
__global__ __launch_bounds__(256)
void conv_mfma_k(const short* __restrict__ Xt, int CinStr,
                 const short* __restrict__ Wt, int Cout,
                 int chunksPerSplit, float* __restrict__ Pout,
                 short* __restrict__ OutBf, int Cstr, int mode)
{
    __shared__ __align__(16) short s_A[64 * 296];      // 37.9 KB  [m][288k +8 pad]
    __shared__ __align__(16) short s_S[4 * 66 * 40];   // 21.1 KB  halo [4r][66px][32ch +8]
    const int tid  = threadIdx.x;
    const int lane = tid & 63, wave = tid >> 6;
    const int lm = lane & 15, quad = lane >> 4;
    const int m0  = blockIdx.x * 64;
    const int r0  = blockIdx.y * 2;
    const int n0g = blockIdx.y * 128;
    const int K   = CinStr * 9;
    const int cb0 = blockIdx.z * chunksPerSplit;
    const int aco = tid & 63, apart = tid >> 6;

    f4v acc[4][2];
#pragma unroll
    for (int ma = 0; ma < 4; ++ma)
#pragma unroll
        for (int fb = 0; fb < 2; ++fb)
#pragma unroll
            for (int r = 0; r < 4; ++r) acc[ma][fb][r] = 0.f;

    for (int cc = 0; cc < chunksPerSplit; ++cc) {
        const int cb = cb0 + cc;
        // ---- stage A tile: 64 co x 288 k ----
        {
            short* adst = s_A + aco * 296 + apart * 72;
            if (m0 + aco < Cout) {
                const short* wsrc = Wt + (size_t)(m0 + aco) * K + cb * 288 + apart * 72;
#pragma unroll
                for (int j = 0; j < 9; ++j)
                    *(uint4*)&adst[j * 8] = *(const uint4*)&wsrc[j * 8];
            } else {
                uint4 z = {0, 0, 0, 0};
#pragma unroll
                for (int j = 0; j < 9; ++j) *(uint4*)&adst[j * 8] = z;
            }
        }
        // ---- stage halo: 4 rows x 66 px x 32 ch (zero-padded) ----
        for (int i = tid; i < 1056; i += 256) {
            int slot = i >> 2, part = i & 3;
            int hr = slot / 66, px = slot % 66;
            int gy = r0 - 1 + hr, gx = px - 1;
            uint4 v = {0, 0, 0, 0};
            if (gy >= 0 && gy < 64 && gx >= 0 && gx < 64)
                v = *(const uint4*)&Xt[(size_t)(gy * 64 + gx) * CinStr + cb * 32 + part * 8];
            *(uint4*)&s_S[slot * 40 + part * 8] = v;
        }
        __syncthreads();

        const int rowsel = wave >> 1;
        const int xbase  = (wave & 1) * 32;
#pragma unroll
        for (int t = 0; t < 9; ++t) {
            const int ty = t / 3, tx = t % 3;
            s8v a[4], b[2];
#pragma unroll
            for (int ma = 0; ma < 4; ++ma)
                a[ma] = *(const s8v*)&s_A[(ma * 16 + lm) * 296 + t * 32 + quad * 8];
#pragma unroll
            for (int fb = 0; fb < 2; ++fb) {
                int px = xbase + fb * 16 + lm + tx;
                b[fb] = *(const s8v*)&s_S[((rowsel + ty) * 66 + px) * 40 + quad * 8];
            }
#pragma unroll
            for (int ma = 0; ma < 4; ++ma)
#pragma unroll
                for (int fb = 0; fb < 2; ++fb)
                    acc[ma][fb] = __builtin_amdgcn_mfma_f32_16x16x32_bf16(
                        a[ma], b[fb], acc[ma][fb], 0, 0, 0);
        }
        __syncthreads();
    }

    // ---- transpose via LDS (alias s_A; 128n x 68m f32 = 34.8 KB) ----
    float* T = (float*)s_A;
#pragma unroll
    for (int ma = 0; ma < 4; ++ma)
#pragma unroll
        for (int fb = 0; fb < 2; ++fb)
#pragma unroll
            for (int r = 0; r < 4; ++r)
                T[(wave * 32 + fb * 16 + lm) * 68 + ma * 16 + quad * 4 + r] = acc[ma][fb][r];
    __syncthreads();

    if (mode == 0) {
        for (int i = tid; i < 2048; i += 256) {
            int n = i >> 4, part = i & 15;
            float4 v = *(const float4*)&T[n * 68 + part * 4];
            *(float4*)&Pout[((size_t)blockIdx.z * HWPX + n0g + n) * Cstr + m0 + part * 4] = v;
        }
    } else {
        for (int i = tid; i < 1024; i += 256) {
            int n = i >> 3, part = i & 7;
            const float* s = &T[n * 68 + part * 8];
            uint4 o;
            o.x = f2bf(s[0]) | ((unsigned)f2bf(s[1]) << 16);
            o.y = f2bf(s[2]) | ((unsigned)f2bf(s[3]) << 16);
            o.z = f2bf(s[4]) | ((unsigned)f2bf(s[5]) << 16);
            o.w = f2bf(s[6]) | ((unsigned)f2bf(s[7]) << 16);
            *(uint4*)&OutBf[(size_t)(n0g + n) * Cstr + m0 + part * 8] = o;
        }
    }
}

// ---------------------------------------------------------------------------
// Epilogue: sum K-split f32 partials, optional relu, -> bf16 pixel-major
// ---------------------------------------------------------------------------
__global__ __launch_bounds__(256)
void ep_sum_k(const float* __restrict__ P, short* __restrict__ outb,
              int nsplit, int n4, int relu)
{
    int i = blockIdx.x * 256 + threadIdx.x;
    if (i >= n4) return;
    size_t base = (size_t)i * 4;
    float4 s = {0.f, 0.f, 0.f, 0.f};
    for (int sp = 0; sp < nsplit; ++sp) {
        float4 v = *(const float4*)&P[(size_t)sp * n4 * 4 + base];
        s.x += v.x; s.y += v.y; s.z += v.z; s.w += v.w;
    }
    if (relu) {
        s.x = fmaxf(s.x, 0.f); s.y = fmaxf(s.y, 0.f);
        s.z = fmaxf(s.z, 0.f); s.w = fmaxf(s.w, 0.f);
    }
    uint2 o;
    o.x = f2bf(s.x) | ((unsigned)f2bf(s.y) << 16);
    o.y = f2bf(s.z) | ((unsigned)f2bf(s.w) << 16);
    *(uint2*)&outb[base] = o;
}

// Epilogue for conv4: partials [8][4096][64] f32 -> offs [18][4096] f32 (co-major)
__global__ __launch_bounds__(256)
void ep_offs_k(const float* __restrict__ P, float* __restrict__ offs)
{
    int i = blockIdx.x * 256 + threadIdx.x;
    if (i >= 18 * HWPX) return;
    int m = i >> 12, px = i & 4095;
    float s = 0.f;
    for (int sp = 0; sp < 8; ++sp) s += P[((size_t)sp * HWPX + px) * 64 + m];
    offs[i] = s;
}

// ---------------------------------------------------------------------------
// Bilinear sampling -> Smp [4096 px][6912 k] bf16, k = cb*288 + t*32 + cl
// Block covers 16 px; meta (4 corner idx + 4 weights per (tap,px)) in LDS.
// ---------------------------------------------------------------------------
__global__ __launch_bounds__(256)
void sample_k(const short* __restrict__ xcat, const float* __restrict__ offs,
              short* __restrict__ Smp)
{
    __shared__ int   s_mi[9][16][4];
    __shared__ float s_mw[9][16][4];
    const int tid = threadIdx.x;
    const int p0  = blockIdx.x * 16;

    if (tid < 144) {
        int t = tid / 16, p = tid % 16;
        int pxg = p0 + p;
        int r = pxg >> 6, x = pxg & 63;
        float dy = offs[(size_t)(2 * t)     * HWPX + pxg];
        float dx = offs[(size_t)(2 * t + 1) * HWPX + pxg];
        float py  = (float)(r - 1 + t / 3) + dy;
        float pxf = (float)(x - 1 + t % 3) + dx;
        py  = fminf(fmaxf(py,  -1e6f), 1e6f);
        pxf = fminf(fmaxf(pxf, -1e6f), 1e6f);
        float y0f = floorf(py), x0f = floorf(pxf);
        float wy1 = py - y0f, wx1 = pxf - x0f;
        float wy0 = 1.f - wy1, wx0 = 1.f - wx1;
        bool vy0 = (y0f >=  0.f) && (y0f <= 63.f);
        bool vy1 = (y0f >= -1.f) && (y0f <= 62.f);
        bool vx0 = (x0f >=  0.f) && (x0f <= 63.f);
        bool vx1 = (x0f >= -1.f) && (x0f <= 62.f);
        int y0 = (int)fminf(fmaxf(y0f,       0.f), 63.f);
        int y1 = (int)fminf(fmaxf(y0f + 1.f, 0.f), 63.f);
        int x0 = (int)fminf(fmaxf(x0f,       0.f), 63.f);
        int x1 = (int)fminf(fmaxf(x0f + 1.f, 0.f), 63.f);
        s_mi[t][p][0] = y0 * 64 + x0;  s_mw[t][p][0] = (vy0 && vx0) ? wy0 * wx0 : 0.f;
        s_mi[t][p][1] = y0 * 64 + x1;  s_mw[t][p][1] = (vy0 && vx1) ? wy0 * wx1 : 0.f;
        s_mi[t][p][2] = y1 * 64 + x0;  s_mw[t][p][2] = (vy1 && vx0) ? wy1 * wx0 : 0.f;
        s_mi[t][p][3] = y1 * 64 + x1;  s_mw[t][p][3] = (vy1 && vx1) ? wy1 * wx1 : 0.f;
    }
    __syncthreads();

    for (int it = 0; it < 54; ++it) {
        int i = it * 256 + tid;                 // 16px * 9t * 96grp = 13824
        int p = i / 864, rest = i % 864;
        int t = rest / 96, g = rest % 96;
        float a[8];
#pragma unroll
        for (int j = 0; j < 8; ++j) a[j] = 0.f;
#pragma unroll
        for (int c = 0; c < 4; ++c) {
            float w = s_mw[t][p][c];
            const short* src = xcat + (size_t)s_mi[t][p][c] * 1536 + 768 + g * 8;
            uint4 v = *(const uint4*)src;
            a[0] += w * bf2f(v.x & 0xffffu); a[1] += w * bf2f(v.x >> 16);
            a[2] += w * bf2f(v.y & 0xffffu); a[3] += w * bf2f(v.y >> 16);
            a[4] += w * bf2f(v.z & 0xffffu); a[5] += w * bf2f(v.z >> 16);
            a[6] += w * bf2f(v.w & 0xffffu); a[7] += w * bf2f(v.w >> 16);
        }
        uint4 o;
        o.x = f2bf(a[0]) | ((unsigned)f2bf(a[1]) << 16);
        o.y = f2bf(a[2]) | ((unsigned)f2bf(a[3]) << 16);
        o.z = f2bf(a[4]) | ((unsigned)f2bf(a[5]) << 16);
        o.w = f2bf(a[6]) | ((unsigned)f2bf(a[7]) << 16);
        *(uint4*)&Smp[(size_t)(p0 + p) * 6912 + (g >> 2) * 288 + t * 32 + (g & 3) * 8] = o;
    }
}

// ---------------------------------------------------------------------------
// Deform GEMM: out[768][4096] f32 = dwt[768][6912] x Smp[4096][6912]^T
// MT=64 x NT=128, A-tile LDS, B-frags direct from global (L2).
// ---------------------------------------------------------------------------
__global__ __launch_bounds__(256)
void dgemm_k(const short* __restrict__ Smp, const short* __restrict__ Wt,
             float* __restrict__ out)
{
    __shared__ __align__(16) short s_A[64 * 296];
    const int tid  = threadIdx.x;
    const int lane = tid & 63, wave = tid >> 6;
    const int lm = lane & 15, quad = lane >> 4;
    const int m0 = blockIdx.x * 64, n0 = blockIdx.y * 128;
    const int aco = tid & 63, apart = tid >> 6;

    f4v acc[4][2];
#pragma unroll
    for (int ma = 0; ma < 4; ++ma)
#pragma unroll
        for (int fb = 0; fb < 2; ++fb)
#pragma unroll
            for (int r = 0; r < 4; ++r) acc[ma][fb][r] = 0.f;

    for (int cb = 0; cb < 24; ++cb) {
        {
            const short* wsrc = Wt + (size_t)(m0 + aco) * 6912 + cb * 288 + apart * 72;
            short* adst = s_A + aco * 296 + apart * 72;
#pragma unroll
            for (int j = 0; j < 9; ++j)
                *(uint4*)&adst[j * 8] = *(const uint4*)&wsrc[j * 8];
        }
        __syncthreads();
        const short* brow = Smp + (size_t)(n0 + wave * 32 + lm) * 6912 + cb * 288 + quad * 8;
#pragma unroll
        for (int t = 0; t < 9; ++t) {
            s8v a[4], b[2];
#pragma unroll
            for (int fb = 0; fb < 2; ++fb)
                b[fb] = *(const s8v*)&brow[(size_t)fb * 16 * 6912 + t * 32];
#pragma unroll
            for (int ma = 0; ma < 4; ++ma)
                a[ma] = *(const s8v*)&s_A[(ma * 16 + lm) * 296 + t * 32 + quad * 8];
#pragma unroll
            for (int ma = 0; ma < 4; ++ma)
#pragma unroll
                for (int fb = 0; fb < 2; ++fb)
                    acc[ma][fb] = __builtin_amdgcn_mfma_f32_16x16x32_bf16(
                        a[ma], b[fb], acc[ma][fb], 0, 0, 0);
        }
        __syncthreads();
    }

#pragma unroll
    for (int ma = 0; ma < 4; ++ma)
#pragma unroll
        for (int fb = 0; fb < 2; ++fb)
#pragma unroll
            for (int r = 0; r < 4; ++r)
                out[(size_t)(m0 + ma * 16 + quad * 4 + r) * HWPX
                    + n0 + wave * 32 + fb * 16 + lm] = acc[ma][fb][r];
}

// ---------------------------------------------------------------------------
extern "C" void kernel_launch(void* const* d_in, const int* in_sizes, int n_in,
                              void* d_out, int out_size, void* d_ws, size_t ws_size,
                              hipStream_t stream)
{
    const float* x_in  = (const float*)d_in[0];
    const float* x_ref = (const float*)d_in[1];
    const float* w1    = (const float*)d_in[2];
    const float* w2    = (const float*)d_in[3];
    const float* w3    = (const float*)d_in[4];
    const float* ow    = (const float*)d_in[5];
    const float* dw    = (const float*)d_in[6];
    float* out = (float*)d_out;

    char* w = (char*)d_ws;
    size_t off = 0;
    auto carve = [&](size_t bytes) {
        void* p = w + off;
        off += (bytes + 255) & ~(size_t)255;
        return p;
    };
    short* xcat = (short*)carve((size_t)4096 * 1536 * 2);
    short* w1t  = (short*)carve((size_t)192 * 13824 * 2);
    short* w2t  = (short*)carve((size_t)192 * 1728 * 2);
    short* w3t  = (short*)carve((size_t)1536 * 1728 * 2);
    short* w4t  = (short*)carve((size_t)18 * 13824 * 2);
    short* dwt  = (short*)carve((size_t)768 * 6912 * 2);
    short* h1t  = (short*)carve((size_t)4096 * 192 * 2);
    short* h2t  = (short*)carve((size_t)4096 * 192 * 2);
    short* est  = (short*)carve((size_t)4096 * 1536 * 2);
    float* offs = (float*)carve((size_t)18 * 4096 * 4);
    short* Smp  = (short*)carve((size_t)4096 * 6912 * 2);
    float* P    = (float*)carve((size_t)3 * 4096 * 192 * 4);   // reused by conv4 (8*4096*64*4)

    tr_cat_k<<<dim3(24, 64), 256, 0, stream>>>(x_in, x_ref, xcat);
    wprep_k<<<(192 * 13824 + 255) / 256, 256, 0, stream>>>(w1, w1t, 1536, 192 * 13824);
    wprep_k<<<(192 * 1728 + 255) / 256, 256, 0, stream>>>(w2, w2t, 192, 192 * 1728);
    wprep_k<<<(1536 * 1728 + 255) / 256, 256, 0, stream>>>(w3, w3t, 192, 1536 * 1728);
    wprep_k<<<(18 * 13824 + 255) / 256, 256, 0, stream>>>(ow, w4t, 1536, 18 * 13824);
    wprep_k<<<(768 * 6912 + 255) / 256, 256, 0, stream>>>(dw, dwt, 768, 768 * 6912);

    const int n4 = 4096 * 192 / 4;
    // conv1: 1536 -> 192, relu; K-split 3 (16 chunks each)
    conv_mfma_k<<<dim3(3, 32, 3), 256, 0, stream>>>(xcat, 1536, w1t, 192, 16, P, nullptr, 192, 0);
    ep_sum_k<<<(n4 + 255) / 256, 256, 0, stream>>>(P, h1t, 3, n4, 1);
    // conv2: 192 -> 192, relu; K-split 3 (2 chunks each)
    conv_mfma_k<<<dim3(3, 32, 3), 256, 0, stream>>>(h1t, 192, w2t, 192, 2, P, nullptr, 192, 0);
    ep_sum_k<<<(n4 + 255) / 256, 256, 0, stream>>>(P, h2t, 3, n4, 1);
    // conv3: 192 -> 1536, no relu, direct bf16
    conv_mfma_k<<<dim3(24, 32, 1), 256, 0, stream>>>(h2t, 192, w3t, 1536, 6, nullptr, est, 1536, 1);
    // conv4: 1536 -> 18 (offsets); K-split 8 (6 chunks each), Cstr=64 partials
    conv_mfma_k<<<dim3(1, 32, 8), 256, 0, stream>>>(est, 1536, w4t, 18, 6, P, nullptr, 64, 0);
    ep_offs_k<<<(18 * HWPX + 255) / 256, 256, 0, stream>>>(P, offs);
    // deformable conv: sample -> im2col bf16, then MFMA GEMM
    sample_k<<<256, 256, 0, stream>>>(xcat, offs, Smp);
    dgemm_k<<<dim3(12, 32), 256, 0, stream>>>(Smp, dwt, out);
}

// Round 4
// 473.107 us; speedup vs baseline: 11.9985x; 1.0682x over previous
//
#include <hip/hip_runtime.h>

#define HWPX 4096   // 64*64 pixels

typedef short s8v  __attribute__((ext_vector_type(8)));   // 8 x bf16 (4 VGPR)
typedef float f4v  __attribute__((ext_vector_type(4)));   // 4 x f32  (MFMA C/D)

__device__ inline unsigned short f2bf(float f) {          // RNE f32 -> bf16
    unsigned u = __float_as_uint(f);
    return (unsigned short)((u + 0x7fffu + ((u >> 16) & 1u)) >> 16);
}
__device__ inline float bf2f(unsigned s) {
    return __uint_as_float(s << 16);
}

// ---------------------------------------------------------------------------
// Transpose+concat+cast: x_in/x_ref [768][4096] f32 -> xcat [4096 px][1536 ch] bf16
// ---------------------------------------------------------------------------
__global__ __launch_bounds__(256)
void tr_cat_k(const float* __restrict__ xa, const float* __restrict__ xb,
              short* __restrict__ xt)
{
    __shared__ __align__(16) short T[64 * 72];
    const int c0 = blockIdx.x * 64, p0 = blockIdx.y * 64, tid = threadIdx.x;
    for (int i = tid; i < 4096; i += 256) {
        int cl = i >> 6, pl = i & 63;
        int c = c0 + cl;
        float v = (c < 768) ? xa[(size_t)c * HWPX + p0 + pl]
                            : xb[(size_t)(c - 768) * HWPX + p0 + pl];
        T[pl * 72 + cl] = (short)f2bf(v);
    }
    __syncthreads();
    for (int i = tid; i < 512; i += 256) {
        int pl = i >> 3, part = i & 7;
        uint4 v = *(const uint4*)&T[pl * 72 + part * 8];
        *(uint4*)&xt[(size_t)(p0 + pl) * 1536 + c0 + part * 8] = v;
    }
}

// ---------------------------------------------------------------------------
// Weight transform: src [Cout][Cin][9] f32 -> dst[co][K] bf16 with
// k = cb*288 + t*32 + cl   (cb = channel chunk of 32, t = tap, cl = ch-in-chunk)
// ---------------------------------------------------------------------------
__global__ __launch_bounds__(256)
void wprep_k(const float* __restrict__ src, short* __restrict__ dst,
             int Cin, int total)
{
    int i = blockIdx.x * 256 + threadIdx.x;
    if (i >= total) return;
    int K = Cin * 9;
    int co = i / K, r = i % K;
    int cb = r / 288, q = r % 288;
    int t = q >> 5, cl = q & 31;
    dst[i] = (short)f2bf(src[((size_t)co * Cin + cb * 32 + cl) * 9 + t]);
}

// ---------------------------------------------------------------------------
// Implicit-GEMM 3x3 conv, MFMA bf16. Block: 128 threads = 2 waves.
// Tile: 64 couts x 128 px (2 image rows). Wave tile 64m x 64n (wave wv owns
// output row r0+wv). K chunked 288 (32 ch x 9 taps); halo 4 rows x 66 px x 32ch.
// mode 0: f32 partials [split][4096][Cstr]; mode 1: bf16 out [4096][Cstr].
// ---------------------------------------------------------------------------
__global__ __launch_bounds__(128)
void conv_mfma_k(const short* __restrict__ Xt, int CinStr,
                 const short* __restrict__ Wt, int Cout,
                 int chunks, float* __restrict__ Pout,
                 short* __restrict__ OutBf, int Cstr, int mode)
{
    __shared__ __align__(16) short smem[64 * 296 + 4 * 66 * 40];  // 59.0 KB
    short* s_A = smem;               // [64][296]
    short* s_S = smem + 64 * 296;    // [4][66][40]
    const int tid  = threadIdx.x;
    const int lane = tid & 63, wv = tid >> 6;        // wv in 0..1
    const int lm = lane & 15, quad = lane >> 4;
    const int m0  = blockIdx.x * 64;
    const int r0  = blockIdx.y * 2;                  // 2 output rows = 128 px
    const int n0g = r0 * 64;
    const int K   = CinStr * 9;
    const int cb0 = blockIdx.z * chunks;
    const int aco = tid & 63, apart = tid >> 6;      // apart in 0..1

    f4v acc[4][4];
#pragma unroll
    for (int ma = 0; ma < 4; ++ma)
#pragma unroll
        for (int nb = 0; nb < 4; ++nb)
#pragma unroll
            for (int r = 0; r < 4; ++r) acc[ma][nb][r] = 0.f;

    for (int cc = 0; cc < chunks; ++cc) {
        const int cb = cb0 + cc;
        // ---- stage A: 64 co x 288 k (each thread 144 shorts = 18 x 16B) ----
        {
            short* adst = s_A + aco * 296 + apart * 144;
            if (m0 + aco < Cout) {
                const short* ws = Wt + (size_t)(m0 + aco) * K + cb * 288 + apart * 144;
#pragma unroll
                for (int j = 0; j < 18; ++j)
                    *(uint4*)&adst[j * 8] = *(const uint4*)&ws[j * 8];
            } else {
                uint4 z = {0, 0, 0, 0};
#pragma unroll
                for (int j = 0; j < 18; ++j) *(uint4*)&adst[j * 8] = z;
            }
        }
        // ---- stage halo: 4 rows x 66 px x 32 ch ----
        for (int i = tid; i < 1056; i += 128) {
            int slot = i >> 2, part = i & 3;
            int hr = slot / 66, px = slot % 66;
            int gy = r0 - 1 + hr, gx = px - 1;
            uint4 v = {0, 0, 0, 0};
            if (gy >= 0 && gy < 64 && gx >= 0 && gx < 64)
                v = *(const uint4*)&Xt[(size_t)(gy * 64 + gx) * CinStr + cb * 32 + part * 8];
            *(uint4*)&s_S[(hr * 66 + px) * 40 + part * 8] = v;
        }
        __syncthreads();

#pragma unroll
        for (int t = 0; t < 9; ++t) {
            const int ty = t / 3, tx = t % 3;
            s8v a[4], b[4];
#pragma unroll
            for (int ma = 0; ma < 4; ++ma)
                a[ma] = *(const s8v*)&s_A[(ma * 16 + lm) * 296 + t * 32 + quad * 8];
#pragma unroll
            for (int nb = 0; nb < 4; ++nb)
                b[nb] = *(const s8v*)&s_S[((wv + ty) * 66 + nb * 16 + lm + tx) * 40 + quad * 8];
#pragma unroll
            for (int ma = 0; ma < 4; ++ma)
#pragma unroll
                for (int nb = 0; nb < 4; ++nb)
                    acc[ma][nb] = __builtin_amdgcn_mfma_f32_16x16x32_bf16(
                        a[ma], b[nb], acc[ma][nb], 0, 0, 0);
        }
        __syncthreads();
    }

    // ---- epilogue: transpose via LDS (f32 T[128][68] = 34.8 KB) ----
    float* T = (float*)smem;
#pragma unroll
    for (int ma = 0; ma < 4; ++ma)
#pragma unroll
        for (int nb = 0; nb < 4; ++nb)
#pragma unroll
            for (int r = 0; r < 4; ++r)
                T[(wv * 64 + nb * 16 + lm) * 68 + ma * 16 + quad * 4 + r] = acc[ma][nb][r];
    __syncthreads();

    if (mode == 0) {
        for (int i = tid; i < 2048; i += 128) {
            int n = i >> 4, part = i & 15;
            float4 v = *(const float4*)&T[n * 68 + part * 4];
            *(float4*)&Pout[((size_t)blockIdx.z * HWPX + n0g + n) * Cstr + m0 + part * 4] = v;
        }
    } else {
        for (int i = tid; i < 1024; i += 128) {
            int n = i >> 3, part = i & 7;
            const float* s = &T[n * 68 + part * 8];
            uint4 o;
            o.x = f2bf(s[0]) | ((unsigned)f2bf(s[1]) << 16);
            o.y = f2bf(s[2]) | ((unsigned)f2bf(s[3]) << 16);
            o.z = f2bf(s[4]) | ((unsigned)f2bf(s[5]) << 16);
            o.w = f2bf(s[6]) | ((unsigned)f2bf(s[7]) << 16);
            *(uint4*)&OutBf[(size_t)(n0g + n) * Cstr + m0 + part * 8] = o;
        }
    }
}

// ---------------------------------------------------------------------------
// Epilogue: sum K-split f32 partials, optional relu, -> bf16 pixel-major
// ---------------------------------------------------------------------------
__global__ __launch_bounds__(256)
void ep_sum_k(const float* __restrict__ P, short* __restrict__ outb,
              int nsplit, int n4, int relu)
{
    int i = blockIdx.x * 256 + threadIdx.x;
    if (i >= n4) return;
    size_t base = (size_t)i * 4;
    float4 s = {0.f, 0.f, 0.f, 0.f};
    for (int sp = 0; sp < nsplit; ++sp) {
        float4 v = *(const float4*)&P[(size_t)sp * n4 * 4 + base];
        s.x += v.x; s.y += v.y; s.z += v.z; s.w += v.w;
    }
    if (relu) {
        s.x = fmaxf(s.x, 0.f); s.y = fmaxf(s.y, 0.f);
        s.z = fmaxf(s.z, 0.f); s.w = fmaxf(s.w, 0.f);
    }
    uint2 o;
    o.x = f2bf(s.x) | ((unsigned)f2bf(s.y) << 16);
    o.y = f2bf(s.z) | ((unsigned)f2bf(s.w) << 16);
    *(uint2*)&outb[base] = o;
}

// Epilogue for conv4: partials [nsplit][4096][64] f32 -> offs [18][4096] f32
__global__ __launch_bounds__(256)
void ep_offs_k(const float* __restrict__ P, float* __restrict__ offs, int nsplit)
{
    int i = blockIdx.x * 256 + threadIdx.x;
    if (i >= 18 * HWPX) return;
    int m = i >> 12, px = i & 4095;
    float s = 0.f;
    for (int sp = 0; sp < nsplit; ++sp) s += P[((size_t)sp * HWPX + px) * 64 + m];
    offs[i] = s;
}

// ---------------------------------------------------------------------------
// Bilinear sampling -> Smp [4096 px][6912 k] bf16, k = cb*288 + t*32 + cl
// ---------------------------------------------------------------------------
__global__ __launch_bounds__(256)
void sample_k(const short* __restrict__ xcat, const float* __restrict__ offs,
              short* __restrict__ Smp)
{
    __shared__ int   s_mi[9][16][4];
    __shared__ float s_mw[9][16][4];
    const int tid = threadIdx.x;
    const int p0  = blockIdx.x * 16;

    if (tid < 144) {
        int t = tid / 16, p = tid % 16;
        int pxg = p0 + p;
        int r = pxg >> 6, x = pxg & 63;
        float dy = offs[(size_t)(2 * t)     * HWPX + pxg];
        float dx = offs[(size_t)(2 * t + 1) * HWPX + pxg];
        float py  = (float)(r - 1 + t / 3) + dy;
        float pxf = (float)(x - 1 + t % 3) + dx;
        py  = fminf(fmaxf(py,  -1e6f), 1e6f);
        pxf = fminf(fmaxf(pxf, -1e6f), 1e6f);
        float y0f = floorf(py), x0f = floorf(pxf);
        float wy1 = py - y0f, wx1 = pxf - x0f;
        float wy0 = 1.f - wy1, wx0 = 1.f - wx1;
        bool vy0 = (y0f >=  0.f) && (y0f <= 63.f);
        bool vy1 = (y0f >= -1.f) && (y0f <= 62.f);
        bool vx0 = (x0f >=  0.f) && (x0f <= 63.f);
        bool vx1 = (x0f >= -1.f) && (x0f <= 62.f);
        int y0 = (int)fminf(fmaxf(y0f,       0.f), 63.f);
        int y1 = (int)fminf(fmaxf(y0f + 1.f, 0.f), 63.f);
        int x0 = (int)fminf(fmaxf(x0f,       0.f), 63.f);
        int x1 = (int)fminf(fmaxf(x0f + 1.f, 0.f), 63.f);
        s_mi[t][p][0] = y0 * 64 + x0;  s_mw[t][p][0] = (vy0 && vx0) ? wy0 * wx0 : 0.f;
        s_mi[t][p][1] = y0 * 64 + x1;  s_mw[t][p][1] = (vy0 && vx1) ? wy0 * wx1 : 0.f;
        s_mi[t][p][2] = y1 * 64 + x0;  s_mw[t][p][2] = (vy1 && vx0) ? wy1 * wx0 : 0.f;
        s_mi[t][p][3] = y1 * 64 + x1;  s_mw[t][p][3] = (vy1 && vx1) ? wy1 * wx1 : 0.f;
    }
    __syncthreads();

    for (int it = 0; it < 54; ++it) {
        int i = it * 256 + tid;                 // 16px * 9t * 96grp = 13824
        int p = i / 864, rest = i % 864;
        int t = rest / 96, g = rest % 96;
        float a[8];
#pragma unroll
        for (int j = 0; j < 8; ++j) a[j] = 0.f;
#pragma unroll
        for (int c = 0; c < 4; ++c) {
            float w = s_mw[t][p][c];
            const short* src = xcat + (size_t)s_mi[t][p][c] * 1536 + 768 + g * 8;
            uint4 v = *(const uint4*)src;
            a[0] += w * bf2f(v.x & 0xffffu); a[1] += w * bf2f(v.x >> 16);
            a[2] += w * bf2f(v.y & 0xffffu); a[3] += w * bf2f(v.y >> 16);
            a[4] += w * bf2f(v.z & 0xffffu); a[5] += w * bf2f(v.z >> 16);
            a[6] += w * bf2f(v.w & 0xffffu); a[7] += w * bf2f(v.w >> 16);
        }
        uint4 o;
        o.x = f2bf(a[0]) | ((unsigned)f2bf(a[1]) << 16);
        o.y = f2bf(a[2]) | ((unsigned)f2bf(a[3]) << 16);
        o.z = f2bf(a[4]) | ((unsigned)f2bf(a[5]) << 16);
        o.w = f2bf(a[6]) | ((unsigned)f2bf(a[7]) << 16);
        *(uint4*)&Smp[(size_t)(p0 + p) * 6912 + (g >> 2) * 288 + t * 32 + (g & 3) * 8] = o;
    }
}

// ---------------------------------------------------------------------------
// Deform GEMM: P[bz][768][4096] f32 partial = dwt[768][Khalf] x Smp[4096][Khalf]^T
// Block 256 thr, tile 128m x 128n, wave 2x2 (wave tile 64x64), BK=64.
// Both A and B staged in LDS (stride 80 shorts). Grid (32 n, 6 m, 2 ksplit):
// n fastest => all blocks of one n-tile land on one XCD (id%8 = n%8).
// ---------------------------------------------------------------------------
__global__ __launch_bounds__(256)
void dgemm_k(const short* __restrict__ Smp, const short* __restrict__ Wt,
             float* __restrict__ P)
{
    __shared__ __align__(16) short sAB[2 * 128 * 80];   // 41.0 KB
    short* sA = sAB;
    short* sB = sAB + 128 * 80;
    const int tid  = threadIdx.x;
    const int lane = tid & 63, wv = tid >> 6;
    const int lm = lane & 15, quad = lane >> 4;
    const int n0 = blockIdx.x * 128, m0 = blockIdx.y * 128;
    const int kb = blockIdx.z * 3456;
    const int mh = (wv >> 1) * 64, nh = (wv & 1) * 64;

    f4v acc[4][4];
#pragma unroll
    for (int ma = 0; ma < 4; ++ma)
#pragma unroll
        for (int nb = 0; nb < 4; ++nb)
#pragma unroll
            for (int r = 0; r < 4; ++r) acc[ma][nb][r] = 0.f;

    for (int c = 0; c < 54; ++c) {
        const int kc = kb + c * 64;
        uint4 ra[4], rb[4];
#pragma unroll
        for (int j = 0; j < 4; ++j) {
            int u = j * 256 + tid, row = u >> 3, part = u & 7;
            ra[j] = *(const uint4*)&Wt[(size_t)(m0 + row) * 6912 + kc + part * 8];
            rb[j] = *(const uint4*)&Smp[(size_t)(n0 + row) * 6912 + kc + part * 8];
        }
#pragma unroll
        for (int j = 0; j < 4; ++j) {
            int u = j * 256 + tid, row = u >> 3, part = u & 7;
            *(uint4*)&sA[row * 80 + part * 8] = ra[j];
            *(uint4*)&sB[row * 80 + part * 8] = rb[j];
        }
        __syncthreads();
#pragma unroll
        for (int ks = 0; ks < 2; ++ks) {
            s8v a[4], b[4];
#pragma unroll
            for (int ma = 0; ma < 4; ++ma)
                a[ma] = *(const s8v*)&sA[(mh + ma * 16 + lm) * 80 + ks * 32 + quad * 8];
#pragma unroll
            for (int nb = 0; nb < 4; ++nb)
                b[nb] = *(const s8v*)&sB[(nh + nb * 16 + lm) * 80 + ks * 32 + quad * 8];
#pragma unroll
            for (int ma = 0; ma < 4; ++ma)
#pragma unroll
                for (int nb = 0; nb < 4; ++nb)
                    acc[ma][nb] = __builtin_amdgcn_mfma_f32_16x16x32_bf16(
                        a[ma], b[nb], acc[ma][nb], 0, 0, 0);
        }
        __syncthreads();
    }

#pragma unroll
    for (int ma = 0; ma < 4; ++ma)
#pragma unroll
        for (int nb = 0; nb < 4; ++nb)
#pragma unroll
            for (int r = 0; r < 4; ++r)
                P[((size_t)blockIdx.z * 768 + m0 + mh + ma * 16 + quad * 4 + r) * HWPX
                  + n0 + nh + nb * 16 + lm] = acc[ma][nb][r];
}

// out = P[0] + P[1]  (768*4096 f32)
__global__ __launch_bounds__(256)
void ep_dg_k(const float* __restrict__ P, float* __restrict__ out)
{
    int i = blockIdx.x * 256 + threadIdx.x;
    if (i >= 768 * HWPX / 4) return;
    size_t base = (size_t)i * 4;
    float4 a = *(const float4*)&P[base];
    float4 b = *(const float4*)&P[(size_t)768 * HWPX + base];
    float4 s = make_float4(a.x + b.x, a.y + b.y, a.z + b.z, a.w + b.w);
    *(float4*)&out[base] = s;
}

// ---------------------------------------------------------------------------
extern "C" void kernel_launch(void* const* d_in, const int* in_sizes, int n_in,
                              void* d_out, int out_size, void* d_ws, size_t ws_size,
                              hipStream_t stream)
{
    const float* x_in  = (const float*)d_in[0];
    const float* x_ref = (const float*)d_in[1];
    const float* w1    = (const float*)d_in[2];
    const float* w2    = (const float*)d_in[3];
    const float* w3    = (const float*)d_in[4];
    const float* ow    = (const float*)d_in[5];
    const float* dw    = (const float*)d_in[6];
    float* out = (float*)d_out;

    char* w = (char*)d_ws;
    size_t off = 0;
    auto carve = [&](size_t bytes) {
        void* p = w + off;
        off += (bytes + 255) & ~(size_t)255;
        return p;
    };
    short* xcat = (short*)carve((size_t)4096 * 1536 * 2);   // 12.58 MB
    short* w1t  = (short*)carve((size_t)192 * 13824 * 2);   //  5.31 MB
    short* w2t  = (short*)carve((size_t)192 * 1728 * 2);    //  0.66 MB
    short* w3t  = (short*)carve((size_t)1536 * 1728 * 2);   //  5.31 MB
    short* w4t  = (short*)carve((size_t)18 * 13824 * 2);    //  0.50 MB
    short* dwt  = (short*)carve((size_t)768 * 6912 * 2);    // 10.62 MB
    float* offs = (float*)carve((size_t)18 * 4096 * 4);     //  0.29 MB
    short* Smp  = (short*)carve((size_t)4096 * 6912 * 2);   // 56.62 MB
    // REGION: 25.17 MB, aliased across phases
    char*  R    = (char*)carve((size_t)2 * 768 * 4096 * 4);
    short* rh1  = (short*)R;                                // h1 bf16 [4096][192]
    short* rh2  = (short*)(R + 1572864);                    // h2 bf16 [4096][192]
    char*  rEst = R + 3145728;                              // est bf16 / conv1 partials
    float* rPc  = (float*)(R + 15728640);                   // conv2/conv4 partials (10.4 MB)
    float* Pdg  = (float*)R;                                // dgemm partials [2][768][4096]

    tr_cat_k<<<dim3(24, 64), 256, 0, stream>>>(x_in, x_ref, xcat);
    wprep_k<<<(192 * 13824 + 255) / 256, 256, 0, stream>>>(w1, w1t, 1536, 192 * 13824);
    wprep_k<<<(192 * 1728 + 255) / 256, 256, 0, stream>>>(w2, w2t, 192, 192 * 1728);
    wprep_k<<<(1536 * 1728 + 255) / 256, 256, 0, stream>>>(w3, w3t, 192, 1536 * 1728);
    wprep_k<<<(18 * 13824 + 255) / 256, 256, 0, stream>>>(ow, w4t, 1536, 18 * 13824);
    wprep_k<<<(768 * 6912 + 255) / 256, 256, 0, stream>>>(dw, dwt, 768, 768 * 6912);

    const int n4 = 4096 * 192 / 4;
    // conv1: 1536 -> 192, relu; ksplit 3 x 16 chunks = 48 (full K)
    conv_mfma_k<<<dim3(3, 32, 3), 128, 0, stream>>>(xcat, 1536, w1t, 192, 16,
                                                    (float*)rEst, nullptr, 192, 0);
    ep_sum_k<<<(n4 + 255) / 256, 256, 0, stream>>>((float*)rEst, rh1, 3, n4, 1);
    // conv2: 192 -> 192, relu; ksplit 2 x 3 chunks = 6 (full K)
    conv_mfma_k<<<dim3(3, 32, 2), 128, 0, stream>>>(rh1, 192, w2t, 192, 3,
                                                    rPc, nullptr, 192, 0);
    ep_sum_k<<<(n4 + 255) / 256, 256, 0, stream>>>(rPc, rh2, 2, n4, 1);
    // conv3: 192 -> 1536, direct bf16 -> est (rEst); 1 x 6 chunks = 6 (full K)
    conv_mfma_k<<<dim3(24, 32, 1), 128, 0, stream>>>(rh2, 192, w3t, 1536, 6,
                                                     nullptr, (short*)rEst, 1536, 1);
    // conv4: 1536 -> 18; ksplit 8 x 6 chunks = 48 (full K); partials [8][4096][64]
    conv_mfma_k<<<dim3(1, 32, 8), 128, 0, stream>>>((short*)rEst, 1536, w4t, 18, 6,
                                                    rPc, nullptr, 64, 0);
    ep_offs_k<<<(18 * HWPX + 255) / 256, 256, 0, stream>>>(rPc, offs, 8);
    // deformable conv: sample -> im2col bf16, then MFMA GEMM (ksplit 2) + sum
    sample_k<<<256, 256, 0, stream>>>(xcat, offs, Smp);
    dgemm_k<<<dim3(32, 6, 2), 256, 0, stream>>>(Smp, dwt, Pdg);
    ep_dg_k<<<(768 * HWPX / 4 + 255) / 256, 256, 0, stream>>>(Pdg, out);
}

// Round 5
// 382.684 us; speedup vs baseline: 14.8336x; 1.2363x over previous
//
#include <hip/hip_runtime.h>

#define HWPX 4096   // 64*64 pixels

typedef short s8v  __attribute__((ext_vector_type(8)));   // 8 x bf16 (4 VGPR)
typedef float f4v  __attribute__((ext_vector_type(4)));   // 4 x f32  (MFMA C/D)

__device__ inline unsigned short f2bf(float f) {          // RNE f32 -> bf16
    unsigned u = __float_as_uint(f);
    return (unsigned short)((u + 0x7fffu + ((u >> 16) & 1u)) >> 16);
}
__device__ inline float bf2f(unsigned s) {
    return __uint_as_float(s << 16);
}

// ---------------------------------------------------------------------------
// Transpose+concat+cast: x_in/x_ref [768][4096] f32 -> xcat [4096 px][1536 ch] bf16
// ---------------------------------------------------------------------------
__global__ __launch_bounds__(256)
void tr_cat_k(const float* __restrict__ xa, const float* __restrict__ xb,
              short* __restrict__ xt)
{
    __shared__ __align__(16) short T[64 * 72];
    const int c0 = blockIdx.x * 64, p0 = blockIdx.y * 64, tid = threadIdx.x;
    for (int i = tid; i < 4096; i += 256) {
        int cl = i >> 6, pl = i & 63;
        int c = c0 + cl;
        float v = (c < 768) ? xa[(size_t)c * HWPX + p0 + pl]
                            : xb[(size_t)(c - 768) * HWPX + p0 + pl];
        T[pl * 72 + cl] = (short)f2bf(v);
    }
    __syncthreads();
    for (int i = tid; i < 512; i += 256) {
        int pl = i >> 3, part = i & 7;
        uint4 v = *(const uint4*)&T[pl * 72 + part * 8];
        *(uint4*)&xt[(size_t)(p0 + pl) * 1536 + c0 + part * 8] = v;
    }
}

// ---------------------------------------------------------------------------
// Weight fragment-pack: src [Cout][Cin][9] f32 ->
// dst[g][s][f][lane][8] bf16 (g = cout group of NB*16, s = k-step = cb*9+t,
// f = n-frag). Lane lm = cout offset, quad = k-part: value =
// W[g*NB*16 + f*16 + lm][cb*32 + quad*8 + e][t]. Zero-padded couts.
// ---------------------------------------------------------------------------
__global__ __launch_bounds__(256)
void wpack_k(const float* __restrict__ src, short* __restrict__ dst,
             int Cin, int Cout, int S, int NB, int total)
{
    int i = blockIdx.x * 256 + threadIdx.x;
    if (i >= total) return;
    int e = i & 7, lane = (i >> 3) & 63;
    int lm = lane & 15, quad = lane >> 4;
    int rest = i >> 9;
    int f = rest % NB;
    int s = (rest / NB) % S;
    int g = rest / (NB * S);
    int cout = g * (NB * 16) + f * 16 + lm;
    int cb = s / 9, t = s % 9;
    int ch = cb * 32 + quad * 8 + e;
    dst[i] = (cout < Cout) ? (short)f2bf(src[((size_t)cout * Cin + ch) * 9 + t]) : 0;
}

// ---------------------------------------------------------------------------
// Flipped implicit-GEMM 3x3 conv, MFMA bf16. Block 256 thr = 4 waves.
// M = pixels (4 rows x 64, wave wv owns row r0+wv, 64 px = 4 m-frags from LDS
// halo), N = 32 couts (2 b-frags direct from fragment-packed weights, global).
// K chunked 32ch x 9 taps. Output bf16 pixel-major [4096][Cstr] (+ split off).
// LDS: halo 6 rows x 66 px x 32 ch (stride 40) = 31.7 KB. No A-LDS, no
// epilogue transpose (D rows = pixels).
// ---------------------------------------------------------------------------
__global__ __launch_bounds__(256, 4)
void convf_k(const short* __restrict__ Xt, int CinStr,
             const short* __restrict__ Wp, int S, int chunks,
             short* __restrict__ Out, int Cstr, int splitStride)
{
    __shared__ __align__(16) short sH[6 * 66 * 40];   // 31.7 KB
    const int tid = threadIdx.x, lane = tid & 63, wv = tid >> 6;
    const int lm = lane & 15, quad = lane >> 4;
    const int r0 = blockIdx.x * 4;            // 4 pixel rows
    const int g  = blockIdx.y;                // cout group of 32
    const int cb0 = blockIdx.z * chunks;
    short* out = Out + (size_t)blockIdx.z * splitStride;

    f4v acc[4][2];
#pragma unroll
    for (int ma = 0; ma < 4; ++ma)
#pragma unroll
        for (int nb = 0; nb < 2; ++nb)
#pragma unroll
            for (int r = 0; r < 4; ++r) acc[ma][nb][r] = 0.f;

    for (int cc = 0; cc < chunks; ++cc) {
        const int cb = cb0 + cc;
        // ---- stage halo: 6 rows x 66 px x 32 ch (zero-padded) ----
        for (int i = tid; i < 1584; i += 256) {
            int slot = i >> 2, part = i & 3;
            int hr = slot / 66, px = slot % 66;
            int gy = r0 - 1 + hr, gx = px - 1;
            uint4 v = {0, 0, 0, 0};
            if (gy >= 0 && gy < 64 && gx >= 0 && gx < 64)
                v = *(const uint4*)&Xt[(size_t)(gy * 64 + gx) * CinStr + cb * 32 + part * 8];
            *(uint4*)&sH[slot * 40 + part * 8] = v;
        }
        __syncthreads();

        const short* wpB = Wp + ((size_t)(g * S + cb * 9) * 2) * 512 + lane * 8;
#pragma unroll
        for (int t = 0; t < 9; ++t) {
            const int ty = t / 3, tx = t % 3;
            s8v a[4], b[2];
            b[0] = *(const s8v*)&wpB[(size_t)(t * 2 + 0) * 512];
            b[1] = *(const s8v*)&wpB[(size_t)(t * 2 + 1) * 512];
#pragma unroll
            for (int ma = 0; ma < 4; ++ma)
                a[ma] = *(const s8v*)&sH[((wv + ty) * 66 + ma * 16 + lm + tx) * 40 + quad * 8];
#pragma unroll
            for (int ma = 0; ma < 4; ++ma) {
                acc[ma][0] = __builtin_amdgcn_mfma_f32_16x16x32_bf16(a[ma], b[0], acc[ma][0], 0, 0, 0);
                acc[ma][1] = __builtin_amdgcn_mfma_f32_16x16x32_bf16(a[ma], b[1], acc[ma][1], 0, 0, 0);
            }
        }
        __syncthreads();
    }

    const int py = (r0 + wv) * 64;
#pragma unroll
    for (int ma = 0; ma < 4; ++ma)
#pragma unroll
        for (int nb = 0; nb < 2; ++nb)
#pragma unroll
            for (int r = 0; r < 4; ++r)
                out[(size_t)(py + ma * 16 + quad * 4 + r) * Cstr + g * 32 + nb * 16 + lm]
                    = (short)f2bf(acc[ma][nb][r]);
}

// ---------------------------------------------------------------------------
// Sum bf16 K-split partials, optional relu, -> bf16
// ---------------------------------------------------------------------------
__global__ __launch_bounds__(256)
void ep_sumb_k(const short* __restrict__ P, short* __restrict__ outb,
               int nsplit, size_t splitStride, int n8, int relu)
{
    int i = blockIdx.x * 256 + threadIdx.x;
    if (i >= n8) return;
    size_t base = (size_t)i * 8;
    float s[8];
#pragma unroll
    for (int j = 0; j < 8; ++j) s[j] = 0.f;
    for (int sp = 0; sp < nsplit; ++sp) {
        uint4 v = *(const uint4*)&P[sp * splitStride + base];
        s[0] += bf2f(v.x & 0xffffu); s[1] += bf2f(v.x >> 16);
        s[2] += bf2f(v.y & 0xffffu); s[3] += bf2f(v.y >> 16);
        s[4] += bf2f(v.z & 0xffffu); s[5] += bf2f(v.z >> 16);
        s[6] += bf2f(v.w & 0xffffu); s[7] += bf2f(v.w >> 16);
    }
    if (relu) {
#pragma unroll
        for (int j = 0; j < 8; ++j) s[j] = fmaxf(s[j], 0.f);
    }
    uint4 o;
    o.x = f2bf(s[0]) | ((unsigned)f2bf(s[1]) << 16);
    o.y = f2bf(s[2]) | ((unsigned)f2bf(s[3]) << 16);
    o.z = f2bf(s[4]) | ((unsigned)f2bf(s[5]) << 16);
    o.w = f2bf(s[6]) | ((unsigned)f2bf(s[7]) << 16);
    *(uint4*)&outb[base] = o;
}

// conv4 epilogue: partials bf16 [16][4096][32] -> offs f32 [18][4096]
__global__ __launch_bounds__(256)
void ep_offs_k(const short* __restrict__ P, float* __restrict__ offs)
{
    int i = blockIdx.x * 256 + threadIdx.x;
    if (i >= 18 * HWPX) return;
    int m = i >> 12, px = i & 4095;
    float s = 0.f;
    for (int sp = 0; sp < 16; ++sp)
        s += bf2f((unsigned short)P[((size_t)sp * HWPX + px) * 32 + m]);
    offs[i] = s;
}

// ---------------------------------------------------------------------------
// Bilinear sampling -> Smp in MFMA fragment-packed order:
// Smp[pg][s][ma][lane][8], pg = px>>6, s = cb*9+t, ma = (px>>4)&3,
// lane = (g&3)*16 + (px&15), 8 channels cl = (g&3)*8.. of chunk cb = g>>2.
// ---------------------------------------------------------------------------
__global__ __launch_bounds__(256)
void sample_k(const short* __restrict__ xcat, const float* __restrict__ offs,
              short* __restrict__ Smp)
{
    __shared__ int   s_mi[9][16][4];
    __shared__ float s_mw[9][16][4];
    const int tid = threadIdx.x;
    const int p0  = blockIdx.x * 16;

    if (tid < 144) {
        int t = tid / 16, p = tid % 16;
        int pxg = p0 + p;
        int r = pxg >> 6, x = pxg & 63;
        float dy = offs[(size_t)(2 * t)     * HWPX + pxg];
        float dx = offs[(size_t)(2 * t + 1) * HWPX + pxg];
        float py  = (float)(r - 1 + t / 3) + dy;
        float pxf = (float)(x - 1 + t % 3) + dx;
        py  = fminf(fmaxf(py,  -1e6f), 1e6f);
        pxf = fminf(fmaxf(pxf, -1e6f), 1e6f);
        float y0f = floorf(py), x0f = floorf(pxf);
        float wy1 = py - y0f, wx1 = pxf - x0f;
        float wy0 = 1.f - wy1, wx0 = 1.f - wx1;
        bool vy0 = (y0f >=  0.f) && (y0f <= 63.f);
        bool vy1 = (y0f >= -1.f) && (y0f <= 62.f);
        bool vx0 = (x0f >=  0.f) && (x0f <= 63.f);
        bool vx1 = (x0f >= -1.f) && (x0f <= 62.f);
        int y0 = (int)fminf(fmaxf(y0f,       0.f), 63.f);
        int y1 = (int)fminf(fmaxf(y0f + 1.f, 0.f), 63.f);
        int x0 = (int)fminf(fmaxf(x0f,       0.f), 63.f);
        int x1 = (int)fminf(fmaxf(x0f + 1.f, 0.f), 63.f);
        s_mi[t][p][0] = y0 * 64 + x0;  s_mw[t][p][0] = (vy0 && vx0) ? wy0 * wx0 : 0.f;
        s_mi[t][p][1] = y0 * 64 + x1;  s_mw[t][p][1] = (vy0 && vx1) ? wy0 * wx1 : 0.f;
        s_mi[t][p][2] = y1 * 64 + x0;  s_mw[t][p][2] = (vy1 && vx0) ? wy1 * wx0 : 0.f;
        s_mi[t][p][3] = y1 * 64 + x1;  s_mw[t][p][3] = (vy1 && vx1) ? wy1 * wx1 : 0.f;
    }
    __syncthreads();

    for (int it = 0; it < 54; ++it) {
        int i = it * 256 + tid;                 // 16px * 9t * 96grp = 13824
        int p = i / 864, rest = i % 864;
        int t = rest / 96, g = rest % 96;
        float a[8];
#pragma unroll
        for (int j = 0; j < 8; ++j) a[j] = 0.f;
#pragma unroll
        for (int c = 0; c < 4; ++c) {
            float w = s_mw[t][p][c];
            const short* src = xcat + (size_t)s_mi[t][p][c] * 1536 + 768 + g * 8;
            uint4 v = *(const uint4*)src;
            a[0] += w * bf2f(v.x & 0xffffu); a[1] += w * bf2f(v.x >> 16);
            a[2] += w * bf2f(v.y & 0xffffu); a[3] += w * bf2f(v.y >> 16);
            a[4] += w * bf2f(v.z & 0xffffu); a[5] += w * bf2f(v.z >> 16);
            a[6] += w * bf2f(v.w & 0xffffu); a[7] += w * bf2f(v.w >> 16);
        }
        uint4 o;
        o.x = f2bf(a[0]) | ((unsigned)f2bf(a[1]) << 16);
        o.y = f2bf(a[2]) | ((unsigned)f2bf(a[3]) << 16);
        o.z = f2bf(a[4]) | ((unsigned)f2bf(a[5]) << 16);
        o.w = f2bf(a[6]) | ((unsigned)f2bf(a[7]) << 16);
        int px = p0 + p;
        int pg = px >> 6, ma = (px >> 4) & 3, lmx = px & 15;
        int cb = g >> 2, qd = g & 3;
        size_t addr = ((((size_t)pg * 216 + cb * 9 + t) * 4 + ma) * 64 + qd * 16 + lmx) * 8;
        *(uint4*)&Smp[addr] = o;
    }
}

// ---------------------------------------------------------------------------
// Deform GEMM, zero-LDS: A = dwp fragment-packed weights [12][216][4][64][8],
// B = Smp fragment-packed samples [64][216][4][64][8]. Block 256 thr = 4
// waves, tile 128co x 128px, wave tile 64x64. K-split 4 (54 steps each),
// bf16 partials [4][768][4096]. All loads coalesced dwordx4 from global.
// ---------------------------------------------------------------------------
__global__ __launch_bounds__(256, 3)
void dgemm_k(const short* __restrict__ Ap, const short* __restrict__ Bp,
             short* __restrict__ P)
{
    const int tid = threadIdx.x, lane = tid & 63, wv = tid >> 6;
    const int lm = lane & 15, quad = lane >> 4;
    const int mg = blockIdx.x * 2 + (wv >> 1);    // 64-cout group 0..11
    const int pg = blockIdx.y * 2 + (wv & 1);     // 64-px group 0..63
    const int s0 = blockIdx.z * 54;
    const short* ap = Ap + (((size_t)mg * 216 + s0) * 4 * 64 + lane) * 8;
    const short* bp = Bp + (((size_t)pg * 216 + s0) * 4 * 64 + lane) * 8;

    f4v acc[4][4];
#pragma unroll
    for (int ma = 0; ma < 4; ++ma)
#pragma unroll
        for (int nb = 0; nb < 4; ++nb)
#pragma unroll
            for (int r = 0; r < 4; ++r) acc[ma][nb][r] = 0.f;

    for (int s = 0; s < 54; ++s) {
        s8v a[4], b[4];
#pragma unroll
        for (int f = 0; f < 4; ++f) {
            a[f] = *(const s8v*)&ap[(size_t)(s * 4 + f) * 512];
            b[f] = *(const s8v*)&bp[(size_t)(s * 4 + f) * 512];
        }
#pragma unroll
        for (int ma = 0; ma < 4; ++ma)
#pragma unroll
            for (int nb = 0; nb < 4; ++nb)
                acc[ma][nb] = __builtin_amdgcn_mfma_f32_16x16x32_bf16(
                    a[ma], b[nb], acc[ma][nb], 0, 0, 0);
    }

    short* p = P + (size_t)blockIdx.z * 768 * HWPX;
#pragma unroll
    for (int ma = 0; ma < 4; ++ma)
#pragma unroll
        for (int nb = 0; nb < 4; ++nb)
#pragma unroll
            for (int r = 0; r < 4; ++r)
                p[(size_t)(mg * 64 + ma * 16 + quad * 4 + r) * HWPX
                  + pg * 64 + nb * 16 + lm] = (short)f2bf(acc[ma][nb][r]);
}

// out f32 = sum of 4 bf16 partials
__global__ __launch_bounds__(256)
void ep_dg_k(const short* __restrict__ P, float* __restrict__ out)
{
    int i = blockIdx.x * 256 + threadIdx.x;
    if (i >= 768 * HWPX / 8) return;
    size_t base = (size_t)i * 8;
    float s[8];
#pragma unroll
    for (int j = 0; j < 8; ++j) s[j] = 0.f;
    for (int sp = 0; sp < 4; ++sp) {
        uint4 v = *(const uint4*)&P[(size_t)sp * 768 * HWPX + base];
        s[0] += bf2f(v.x & 0xffffu); s[1] += bf2f(v.x >> 16);
        s[2] += bf2f(v.y & 0xffffu); s[3] += bf2f(v.y >> 16);
        s[4] += bf2f(v.z & 0xffffu); s[5] += bf2f(v.z >> 16);
        s[6] += bf2f(v.w & 0xffffu); s[7] += bf2f(v.w >> 16);
    }
    float4 o0 = make_float4(s[0], s[1], s[2], s[3]);
    float4 o1 = make_float4(s[4], s[5], s[6], s[7]);
    *(float4*)&out[base]     = o0;
    *(float4*)&out[base + 4] = o1;
}

// ---------------------------------------------------------------------------
extern "C" void kernel_launch(void* const* d_in, const int* in_sizes, int n_in,
                              void* d_out, int out_size, void* d_ws, size_t ws_size,
                              hipStream_t stream)
{
    const float* x_in  = (const float*)d_in[0];
    const float* x_ref = (const float*)d_in[1];
    const float* w1    = (const float*)d_in[2];
    const float* w2    = (const float*)d_in[3];
    const float* w3    = (const float*)d_in[4];
    const float* ow    = (const float*)d_in[5];
    const float* dw    = (const float*)d_in[6];
    float* out = (float*)d_out;

    char* w = (char*)d_ws;
    size_t off = 0;
    auto carve = [&](size_t bytes) {
        void* p = w + off;
        off += (bytes + 255) & ~(size_t)255;
        return p;
    };
    short* xcat = (short*)carve((size_t)4096 * 1536 * 2);        // 12.58 MB
    short* w1p  = (short*)carve((size_t)6 * 432 * 2 * 512 * 2);  //  5.31 MB
    short* w2p  = (short*)carve((size_t)6 * 54 * 2 * 512 * 2);   //  0.66 MB
    short* w3p  = (short*)carve((size_t)48 * 54 * 2 * 512 * 2);  //  5.31 MB
    short* w4p  = (short*)carve((size_t)1 * 432 * 2 * 512 * 2);  //  0.88 MB
    short* dwp  = (short*)carve((size_t)12 * 216 * 4 * 512 * 2); // 10.62 MB
    float* offs = (float*)carve((size_t)18 * 4096 * 4);          //  0.29 MB
    short* Smp  = (short*)carve((size_t)4096 * 6912 * 2);        // 56.62 MB (packed)
    // REGION R: 25.17 MB, aliased across phases
    char*  R    = (char*)carve((size_t)2 * 768 * 4096 * 4);
    short* rh1  = (short*)R;                    // [4096][192] bf16
    short* rh2  = (short*)(R + 1572864);        // [4096][192] bf16
    short* Pb   = (short*)(R + 3145728);        // conv1 partials [12][4096][192] (18.9MB)
                                                //  / conv2 partials [6][...] / est
    short* est  = (short*)(R + 3145728);        // [4096][1536] bf16 (12.58 MB)
    short* Pb4  = (short*)(R + 15728640);       // conv4 partials [16][4096][32] (4.2MB)
    short* Pdg  = (short*)R;                    // dgemm partials [4][768][4096] bf16

    tr_cat_k<<<dim3(24, 64), 256, 0, stream>>>(x_in, x_ref, xcat);
    // fragment-packed weights
    {
        int t1 = 6 * 432 * 2 * 512;
        wpack_k<<<(t1 + 255) / 256, 256, 0, stream>>>(w1, w1p, 1536, 192, 432, 2, t1);
        int t2 = 6 * 54 * 2 * 512;
        wpack_k<<<(t2 + 255) / 256, 256, 0, stream>>>(w2, w2p, 192, 192, 54, 2, t2);
        int t3 = 48 * 54 * 2 * 512;
        wpack_k<<<(t3 + 255) / 256, 256, 0, stream>>>(w3, w3p, 192, 1536, 54, 2, t3);
        int t4 = 1 * 432 * 2 * 512;
        wpack_k<<<(t4 + 255) / 256, 256, 0, stream>>>(ow, w4p, 1536, 18, 432, 2, t4);
        int t5 = 12 * 216 * 4 * 512;
        wpack_k<<<(t5 + 255) / 256, 256, 0, stream>>>(dw, dwp, 768, 768, 216, 4, t5);
    }

    const int n8 = 4096 * 192 / 8;
    // conv1: 1536->192 relu; ksplit 12 x 4 chunks; bf16 partials
    convf_k<<<dim3(16, 6, 12), 256, 0, stream>>>(xcat, 1536, w1p, 432, 4,
                                                 Pb, 192, 4096 * 192);
    ep_sumb_k<<<(n8 + 255) / 256, 256, 0, stream>>>(Pb, rh1, 12, (size_t)4096 * 192, n8, 1);
    // conv2: 192->192 relu; ksplit 6 x 1 chunk
    convf_k<<<dim3(16, 6, 6), 256, 0, stream>>>(rh1, 192, w2p, 54, 1,
                                                Pb, 192, 4096 * 192);
    ep_sumb_k<<<(n8 + 255) / 256, 256, 0, stream>>>(Pb, rh2, 6, (size_t)4096 * 192, n8, 1);
    // conv3: 192->1536, no split, direct bf16
    convf_k<<<dim3(16, 48, 1), 256, 0, stream>>>(rh2, 192, w3p, 54, 6,
                                                 est, 1536, 0);
    // conv4: 1536->18(pad 32); ksplit 16 x 3 chunks
    convf_k<<<dim3(16, 1, 16), 256, 0, stream>>>(est, 1536, w4p, 432, 3,
                                                 Pb4, 32, 4096 * 32);
    ep_offs_k<<<(18 * HWPX + 255) / 256, 256, 0, stream>>>(Pb4, offs);
    // deformable conv: fragment-packed sampling, zero-LDS GEMM, ksplit 4
    sample_k<<<256, 256, 0, stream>>>(xcat, offs, Smp);
    dgemm_k<<<dim3(6, 32, 4), 256, 0, stream>>>(dwp, Smp, Pdg);
    ep_dg_k<<<(768 * HWPX / 8 + 255) / 256, 256, 0, stream>>>(Pdg, out);
}

// Round 6
// 361.571 us; speedup vs baseline: 15.6998x; 1.0584x over previous
//
#include <hip/hip_runtime.h>

#define HWPX 4096   // 64*64 pixels

typedef short s8v  __attribute__((ext_vector_type(8)));   // 8 x bf16 (4 VGPR)
typedef float f4v  __attribute__((ext_vector_type(4)));   // 4 x f32  (MFMA C/D)

__device__ inline unsigned short f2bf(float f) {          // RNE f32 -> bf16
    unsigned u = __float_as_uint(f);
    return (unsigned short)((u + 0x7fffu + ((u >> 16) & 1u)) >> 16);
}
__device__ inline float bf2f(unsigned s) {
    return __uint_as_float(s << 16);
}

// ---------------------------------------------------------------------------
// Transpose+concat+cast: x_in/x_ref [768][4096] f32 -> xcat [4096 px][1536 ch] bf16
// ---------------------------------------------------------------------------
__global__ __launch_bounds__(256)
void tr_cat_k(const float* __restrict__ xa, const float* __restrict__ xb,
              short* __restrict__ xt)
{
    __shared__ __align__(16) short T[64 * 72];
    const int c0 = blockIdx.x * 64, p0 = blockIdx.y * 64, tid = threadIdx.x;
    for (int i = tid; i < 4096; i += 256) {
        int cl = i >> 6, pl = i & 63;
        int c = c0 + cl;
        float v = (c < 768) ? xa[(size_t)c * HWPX + p0 + pl]
                            : xb[(size_t)(c - 768) * HWPX + p0 + pl];
        T[pl * 72 + cl] = (short)f2bf(v);
    }
    __syncthreads();
    for (int i = tid; i < 512; i += 256) {
        int pl = i >> 3, part = i & 7;
        uint4 v = *(const uint4*)&T[pl * 72 + part * 8];
        *(uint4*)&xt[(size_t)(p0 + pl) * 1536 + c0 + part * 8] = v;
    }
}

// ---------------------------------------------------------------------------
// Weight fragment-pack: src [Cout][Cin][9] f32 ->
// dst[g][s][f][lane][8] bf16 (g = cout group of NB*16, s = k-step = cb*9+t,
// f = n-frag). Lane lm = cout offset, quad = k-part.
// ---------------------------------------------------------------------------
__global__ __launch_bounds__(256)
void wpack_k(const float* __restrict__ src, short* __restrict__ dst,
             int Cin, int Cout, int S, int NB, int total)
{
    int i = blockIdx.x * 256 + threadIdx.x;
    if (i >= total) return;
    int e = i & 7, lane = (i >> 3) & 63;
    int lm = lane & 15, quad = lane >> 4;
    int rest = i >> 9;
    int f = rest % NB;
    int s = (rest / NB) % S;
    int g = rest / (NB * S);
    int cout = g * (NB * 16) + f * 16 + lm;
    int cb = s / 9, t = s % 9;
    int ch = cb * 32 + quad * 8 + e;
    dst[i] = (cout < Cout) ? (short)f2bf(src[((size_t)cout * Cin + ch) * 9 + t]) : 0;
}

// ---------------------------------------------------------------------------
// Flipped implicit-GEMM 3x3 conv, MFMA bf16. Block 256 thr = 4 waves.
// M = pixels (4 rows x 64), N = 32 couts (fragment-packed weights from global).
// LDS: halo 6 rows x 66 px x 32 ch (stride 40) = 31.7 KB.
// ---------------------------------------------------------------------------
__global__ __launch_bounds__(256, 4)
void convf_k(const short* __restrict__ Xt, int CinStr,
             const short* __restrict__ Wp, int S, int chunks,
             short* __restrict__ Out, int Cstr, int splitStride)
{
    __shared__ __align__(16) short sH[6 * 66 * 40];   // 31.7 KB
    const int tid = threadIdx.x, lane = tid & 63, wv = tid >> 6;
    const int lm = lane & 15, quad = lane >> 4;
    const int r0 = blockIdx.x * 4;            // 4 pixel rows
    const int g  = blockIdx.y;                // cout group of 32
    const int cb0 = blockIdx.z * chunks;
    short* out = Out + (size_t)blockIdx.z * splitStride;

    f4v acc[4][2];
#pragma unroll
    for (int ma = 0; ma < 4; ++ma)
#pragma unroll
        for (int nb = 0; nb < 2; ++nb)
#pragma unroll
            for (int r = 0; r < 4; ++r) acc[ma][nb][r] = 0.f;

    for (int cc = 0; cc < chunks; ++cc) {
        const int cb = cb0 + cc;
        // ---- stage halo: 6 rows x 66 px x 32 ch (zero-padded) ----
        for (int i = tid; i < 1584; i += 256) {
            int slot = i >> 2, part = i & 3;
            int hr = slot / 66, px = slot % 66;
            int gy = r0 - 1 + hr, gx = px - 1;
            uint4 v = {0, 0, 0, 0};
            if (gy >= 0 && gy < 64 && gx >= 0 && gx < 64)
                v = *(const uint4*)&Xt[(size_t)(gy * 64 + gx) * CinStr + cb * 32 + part * 8];
            *(uint4*)&sH[slot * 40 + part * 8] = v;
        }
        __syncthreads();

        const short* wpB = Wp + ((size_t)(g * S + cb * 9) * 2) * 512 + lane * 8;
#pragma unroll
        for (int t = 0; t < 9; ++t) {
            const int ty = t / 3, tx = t % 3;
            s8v a[4], b[2];
            b[0] = *(const s8v*)&wpB[(size_t)(t * 2 + 0) * 512];
            b[1] = *(const s8v*)&wpB[(size_t)(t * 2 + 1) * 512];
#pragma unroll
            for (int ma = 0; ma < 4; ++ma)
                a[ma] = *(const s8v*)&sH[((wv + ty) * 66 + ma * 16 + lm + tx) * 40 + quad * 8];
#pragma unroll
            for (int ma = 0; ma < 4; ++ma) {
                acc[ma][0] = __builtin_amdgcn_mfma_f32_16x16x32_bf16(a[ma], b[0], acc[ma][0], 0, 0, 0);
                acc[ma][1] = __builtin_amdgcn_mfma_f32_16x16x32_bf16(a[ma], b[1], acc[ma][1], 0, 0, 0);
            }
        }
        __syncthreads();
    }

    const int py = (r0 + wv) * 64;
#pragma unroll
    for (int ma = 0; ma < 4; ++ma)
#pragma unroll
        for (int nb = 0; nb < 2; ++nb)
#pragma unroll
            for (int r = 0; r < 4; ++r)
                out[(size_t)(py + ma * 16 + quad * 4 + r) * Cstr + g * 32 + nb * 16 + lm]
                    = (short)f2bf(acc[ma][nb][r]);
}

// ---------------------------------------------------------------------------
// Sum bf16 K-split partials, optional relu, -> bf16
// ---------------------------------------------------------------------------
__global__ __launch_bounds__(256)
void ep_sumb_k(const short* __restrict__ P, short* __restrict__ outb,
               int nsplit, size_t splitStride, int n8, int relu)
{
    int i = blockIdx.x * 256 + threadIdx.x;
    if (i >= n8) return;
    size_t base = (size_t)i * 8;
    float s[8];
#pragma unroll
    for (int j = 0; j < 8; ++j) s[j] = 0.f;
    for (int sp = 0; sp < nsplit; ++sp) {
        uint4 v = *(const uint4*)&P[sp * splitStride + base];
        s[0] += bf2f(v.x & 0xffffu); s[1] += bf2f(v.x >> 16);
        s[2] += bf2f(v.y & 0xffffu); s[3] += bf2f(v.y >> 16);
        s[4] += bf2f(v.z & 0xffffu); s[5] += bf2f(v.z >> 16);
        s[6] += bf2f(v.w & 0xffffu); s[7] += bf2f(v.w >> 16);
    }
    if (relu) {
#pragma unroll
        for (int j = 0; j < 8; ++j) s[j] = fmaxf(s[j], 0.f);
    }
    uint4 o;
    o.x = f2bf(s[0]) | ((unsigned)f2bf(s[1]) << 16);
    o.y = f2bf(s[2]) | ((unsigned)f2bf(s[3]) << 16);
    o.z = f2bf(s[4]) | ((unsigned)f2bf(s[5]) << 16);
    o.w = f2bf(s[6]) | ((unsigned)f2bf(s[7]) << 16);
    *(uint4*)&outb[base] = o;
}

// conv4 epilogue: partials bf16 [16][4096][32] -> offs f32 [18][4096]
__global__ __launch_bounds__(256)
void ep_offs_k(const short* __restrict__ P, float* __restrict__ offs)
{
    int i = blockIdx.x * 256 + threadIdx.x;
    if (i >= 18 * HWPX) return;
    int m = i >> 12, px = i & 4095;
    float s = 0.f;
    for (int sp = 0; sp < 16; ++sp)
        s += bf2f((unsigned short)P[((size_t)sp * HWPX + px) * 32 + m]);
    offs[i] = s;
}

// ---------------------------------------------------------------------------
// Bilinear sampling -> Smp in MFMA fragment-packed order:
// Smp[pg][s][ma][lane][8]. Grid (256 px-blocks, 4 g-quarters).
// ---------------------------------------------------------------------------
__global__ __launch_bounds__(256)
void sample_k(const short* __restrict__ xcat, const float* __restrict__ offs,
              short* __restrict__ Smp)
{
    __shared__ int   s_mi[9][16][4];
    __shared__ float s_mw[9][16][4];
    const int tid = threadIdx.x;
    const int p0  = blockIdx.x * 16;
    const int gb  = blockIdx.y * 24;   // 24 of 96 channel-groups

    if (tid < 144) {
        int t = tid / 16, p = tid % 16;
        int pxg = p0 + p;
        int r = pxg >> 6, x = pxg & 63;
        float dy = offs[(size_t)(2 * t)     * HWPX + pxg];
        float dx = offs[(size_t)(2 * t + 1) * HWPX + pxg];
        float py  = (float)(r - 1 + t / 3) + dy;
        float pxf = (float)(x - 1 + t % 3) + dx;
        py  = fminf(fmaxf(py,  -1e6f), 1e6f);
        pxf = fminf(fmaxf(pxf, -1e6f), 1e6f);
        float y0f = floorf(py), x0f = floorf(pxf);
        float wy1 = py - y0f, wx1 = pxf - x0f;
        float wy0 = 1.f - wy1, wx0 = 1.f - wx1;
        bool vy0 = (y0f >=  0.f) && (y0f <= 63.f);
        bool vy1 = (y0f >= -1.f) && (y0f <= 62.f);
        bool vx0 = (x0f >=  0.f) && (x0f <= 63.f);
        bool vx1 = (x0f >= -1.f) && (x0f <= 62.f);
        int y0 = (int)fminf(fmaxf(y0f,       0.f), 63.f);
        int y1 = (int)fminf(fmaxf(y0f + 1.f, 0.f), 63.f);
        int x0 = (int)fminf(fmaxf(x0f,       0.f), 63.f);
        int x1 = (int)fminf(fmaxf(x0f + 1.f, 0.f), 63.f);
        s_mi[t][p][0] = y0 * 64 + x0;  s_mw[t][p][0] = (vy0 && vx0) ? wy0 * wx0 : 0.f;
        s_mi[t][p][1] = y0 * 64 + x1;  s_mw[t][p][1] = (vy0 && vx1) ? wy0 * wx1 : 0.f;
        s_mi[t][p][2] = y1 * 64 + x0;  s_mw[t][p][2] = (vy1 && vx0) ? wy1 * wx0 : 0.f;
        s_mi[t][p][3] = y1 * 64 + x1;  s_mw[t][p][3] = (vy1 && vx1) ? wy1 * wx1 : 0.f;
    }
    __syncthreads();

    for (int i = tid; i < 16 * 9 * 24; i += 256) {
        int p = i / 216, rest = i % 216;
        int t = rest / 24, g = gb + rest % 24;
        float a[8];
#pragma unroll
        for (int j = 0; j < 8; ++j) a[j] = 0.f;
#pragma unroll
        for (int c = 0; c < 4; ++c) {
            float w = s_mw[t][p][c];
            const short* src = xcat + (size_t)s_mi[t][p][c] * 1536 + 768 + g * 8;
            uint4 v = *(const uint4*)src;
            a[0] += w * bf2f(v.x & 0xffffu); a[1] += w * bf2f(v.x >> 16);
            a[2] += w * bf2f(v.y & 0xffffu); a[3] += w * bf2f(v.y >> 16);
            a[4] += w * bf2f(v.z & 0xffffu); a[5] += w * bf2f(v.z >> 16);
            a[6] += w * bf2f(v.w & 0xffffu); a[7] += w * bf2f(v.w >> 16);
        }
        uint4 o;
        o.x = f2bf(a[0]) | ((unsigned)f2bf(a[1]) << 16);
        o.y = f2bf(a[2]) | ((unsigned)f2bf(a[3]) << 16);
        o.z = f2bf(a[4]) | ((unsigned)f2bf(a[5]) << 16);
        o.w = f2bf(a[6]) | ((unsigned)f2bf(a[7]) << 16);
        int px = p0 + p;
        int pg = px >> 6, ma = (px >> 4) & 3, lmx = px & 15;
        int cb = g >> 2, qd = g & 3;
        size_t addr = ((((size_t)pg * 216 + cb * 9 + t) * 4 + ma) * 64 + qd * 16 + lmx) * 8;
        *(uint4*)&Smp[addr] = o;
    }
}

// ---------------------------------------------------------------------------
// Deform GEMM, zero-LDS. Grid (32 n, 6 m, 4 ksplit): n fastest => the 6
// m-blocks sharing an Smp n-tile differ by 32/192 in linear id (both ≡0 mod 8)
// => same XCD => B-tile L2-resident, fetched from HBM once.
// ---------------------------------------------------------------------------
__global__ __launch_bounds__(256, 3)
void dgemm_k(const short* __restrict__ Ap, const short* __restrict__ Bp,
             short* __restrict__ P)
{
    const int tid = threadIdx.x, lane = tid & 63, wv = tid >> 6;
    const int lm = lane & 15, quad = lane >> 4;
    const int mg = blockIdx.y * 2 + (wv >> 1);    // 64-cout group 0..11
    const int pg = blockIdx.x * 2 + (wv & 1);     // 64-px group 0..63
    const int s0 = blockIdx.z * 54;
    const short* ap = Ap + (((size_t)mg * 216 + s0) * 4 * 64 + lane) * 8;
    const short* bp = Bp + (((size_t)pg * 216 + s0) * 4 * 64 + lane) * 8;

    f4v acc[4][4];
#pragma unroll
    for (int ma = 0; ma < 4; ++ma)
#pragma unroll
        for (int nb = 0; nb < 4; ++nb)
#pragma unroll
            for (int r = 0; r < 4; ++r) acc[ma][nb][r] = 0.f;

    for (int s = 0; s < 54; ++s) {
        s8v a[4], b[4];
#pragma unroll
        for (int f = 0; f < 4; ++f) {
            a[f] = *(const s8v*)&ap[(size_t)(s * 4 + f) * 512];
            b[f] = *(const s8v*)&bp[(size_t)(s * 4 + f) * 512];
        }
#pragma unroll
        for (int ma = 0; ma < 4; ++ma)
#pragma unroll
            for (int nb = 0; nb < 4; ++nb)
                acc[ma][nb] = __builtin_amdgcn_mfma_f32_16x16x32_bf16(
                    a[ma], b[nb], acc[ma][nb], 0, 0, 0);
    }

    short* p = P + (size_t)blockIdx.z * 768 * HWPX;
#pragma unroll
    for (int ma = 0; ma < 4; ++ma)
#pragma unroll
        for (int nb = 0; nb < 4; ++nb)
#pragma unroll
            for (int r = 0; r < 4; ++r)
                p[(size_t)(mg * 64 + ma * 16 + quad * 4 + r) * HWPX
                  + pg * 64 + nb * 16 + lm] = (short)f2bf(acc[ma][nb][r]);
}

// out f32 = sum of 4 bf16 partials
__global__ __launch_bounds__(256)
void ep_dg_k(const short* __restrict__ P, float* __restrict__ out)
{
    int i = blockIdx.x * 256 + threadIdx.x;
    if (i >= 768 * HWPX / 8) return;
    size_t base = (size_t)i * 8;
    float s[8];
#pragma unroll
    for (int j = 0; j < 8; ++j) s[j] = 0.f;
    for (int sp = 0; sp < 4; ++sp) {
        uint4 v = *(const uint4*)&P[(size_t)sp * 768 * HWPX + base];
        s[0] += bf2f(v.x & 0xffffu); s[1] += bf2f(v.x >> 16);
        s[2] += bf2f(v.y & 0xffffu); s[3] += bf2f(v.y >> 16);
        s[4] += bf2f(v.z & 0xffffu); s[5] += bf2f(v.z >> 16);
        s[6] += bf2f(v.w & 0xffffu); s[7] += bf2f(v.w >> 16);
    }
    float4 o0 = make_float4(s[0], s[1], s[2], s[3]);
    float4 o1 = make_float4(s[4], s[5], s[6], s[7]);
    *(float4*)&out[base]     = o0;
    *(float4*)&out[base + 4] = o1;
}

// ---------------------------------------------------------------------------
extern "C" void kernel_launch(void* const* d_in, const int* in_sizes, int n_in,
                              void* d_out, int out_size, void* d_ws, size_t ws_size,
                              hipStream_t stream)
{
    const float* x_in  = (const float*)d_in[0];
    const float* x_ref = (const float*)d_in[1];
    const float* w1    = (const float*)d_in[2];
    const float* w2    = (const float*)d_in[3];
    const float* w3    = (const float*)d_in[4];
    const float* ow    = (const float*)d_in[5];
    const float* dw    = (const float*)d_in[6];
    float* out = (float*)d_out;

    char* w = (char*)d_ws;
    size_t off = 0;
    auto carve = [&](size_t bytes) {
        void* p = w + off;
        off += (bytes + 255) & ~(size_t)255;
        return p;
    };
    short* xcat = (short*)carve((size_t)4096 * 1536 * 2);        // 12.58 MB
    short* w1p  = (short*)carve((size_t)6 * 432 * 2 * 512 * 2);  //  5.31 MB
    short* w2p  = (short*)carve((size_t)6 * 54 * 2 * 512 * 2);   //  0.66 MB
    short* w3p  = (short*)carve((size_t)48 * 54 * 2 * 512 * 2);  //  5.31 MB
    short* w4p  = (short*)carve((size_t)1 * 432 * 2 * 512 * 2);  //  0.88 MB
    short* dwp  = (short*)carve((size_t)12 * 216 * 4 * 512 * 2); // 10.62 MB
    float* offs = (float*)carve((size_t)18 * 4096 * 4);          //  0.29 MB
    short* Smp  = (short*)carve((size_t)4096 * 6912 * 2);        // 56.62 MB (packed)
    // REGION R: 25.17 MB, aliased across phases
    char*  R    = (char*)carve((size_t)2 * 768 * 4096 * 4);
    short* rh1  = (short*)R;                    // [4096][192] bf16
    short* rh2  = (short*)(R + 1572864);        // [4096][192] bf16
    short* Pb   = (short*)(R + 3145728);        // conv1 partials [12][4096][192]
    short* est  = (short*)(R + 3145728);        // [4096][1536] bf16
    short* Pb4  = (short*)(R + 15728640);       // conv4 partials [16][4096][32]
    short* Pdg  = (short*)R;                    // dgemm partials [4][768][4096] bf16

    tr_cat_k<<<dim3(24, 64), 256, 0, stream>>>(x_in, x_ref, xcat);
    // fragment-packed weights
    {
        int t1 = 6 * 432 * 2 * 512;
        wpack_k<<<(t1 + 255) / 256, 256, 0, stream>>>(w1, w1p, 1536, 192, 432, 2, t1);
        int t2 = 6 * 54 * 2 * 512;
        wpack_k<<<(t2 + 255) / 256, 256, 0, stream>>>(w2, w2p, 192, 192, 54, 2, t2);
        int t3 = 48 * 54 * 2 * 512;
        wpack_k<<<(t3 + 255) / 256, 256, 0, stream>>>(w3, w3p, 192, 1536, 54, 2, t3);
        int t4 = 1 * 432 * 2 * 512;
        wpack_k<<<(t4 + 255) / 256, 256, 0, stream>>>(ow, w4p, 1536, 18, 432, 2, t4);
        int t5 = 12 * 216 * 4 * 512;
        wpack_k<<<(t5 + 255) / 256, 256, 0, stream>>>(dw, dwp, 768, 768, 216, 4, t5);
    }

    const int n8 = 4096 * 192 / 8;
    // conv1: 1536->192 relu; ksplit 12 x 4 chunks; bf16 partials
    convf_k<<<dim3(16, 6, 12), 256, 0, stream>>>(xcat, 1536, w1p, 432, 4,
                                                 Pb, 192, 4096 * 192);
    ep_sumb_k<<<(n8 + 255) / 256, 256, 0, stream>>>(Pb, rh1, 12, (size_t)4096 * 192, n8, 1);
    // conv2: 192->192 relu; ksplit 6 x 1 chunk
    convf_k<<<dim3(16, 6, 6), 256, 0, stream>>>(rh1, 192, w2p, 54, 1,
                                                Pb, 192, 4096 * 192);
    ep_sumb_k<<<(n8 + 255) / 256, 256, 0, stream>>>(Pb, rh2, 6, (size_t)4096 * 192, n8, 1);
    // conv3: 192->1536, no split, direct bf16
    convf_k<<<dim3(16, 48, 1), 256, 0, stream>>>(rh2, 192, w3p, 54, 6,
                                                 est, 1536, 0);
    // conv4: 1536->18(pad 32); ksplit 16 x 3 chunks
    convf_k<<<dim3(16, 1, 16), 256, 0, stream>>>(est, 1536, w4p, 432, 3,
                                                 Pb4, 32, 4096 * 32);
    ep_offs_k<<<(18 * HWPX + 255) / 256, 256, 0, stream>>>(Pb4, offs);
    // deformable conv: fragment-packed sampling (4 g-quarters), zero-LDS GEMM
    sample_k<<<dim3(256, 4), 256, 0, stream>>>(xcat, offs, Smp);
    dgemm_k<<<dim3(32, 6, 4), 256, 0, stream>>>(dwp, Smp, Pdg);
    ep_dg_k<<<(768 * HWPX / 8 + 255) / 256, 256, 0, stream>>>(Pdg, out);
}

// Round 7
// 355.461 us; speedup vs baseline: 15.9697x; 1.0172x over previous
//
#include <hip/hip_runtime.h>

#define HWPX 4096   // 64*64 pixels

typedef short s8v  __attribute__((ext_vector_type(8)));   // 8 x bf16 (4 VGPR)
typedef float f4v  __attribute__((ext_vector_type(4)));   // 4 x f32  (MFMA C/D)

__device__ inline unsigned short f2bf(float f) {          // RNE f32 -> bf16
    unsigned u = __float_as_uint(f);
    return (unsigned short)((u + 0x7fffu + ((u >> 16) & 1u)) >> 16);
}
__device__ inline float bf2f(unsigned s) {
    return __uint_as_float(s << 16);
}

// ---------------------------------------------------------------------------
// Transpose+concat+cast: x_in/x_ref [768][4096] f32 -> xcat [4096 px][1536 ch] bf16
// ---------------------------------------------------------------------------
__global__ __launch_bounds__(256)
void tr_cat_k(const float* __restrict__ xa, const float* __restrict__ xb,
              short* __restrict__ xt)
{
    __shared__ __align__(16) short T[64 * 72];
    const int c0 = blockIdx.x * 64, p0 = blockIdx.y * 64, tid = threadIdx.x;
    for (int i = tid; i < 4096; i += 256) {
        int cl = i >> 6, pl = i & 63;
        int c = c0 + cl;
        float v = (c < 768) ? xa[(size_t)c * HWPX + p0 + pl]
                            : xb[(size_t)(c - 768) * HWPX + p0 + pl];
        T[pl * 72 + cl] = (short)f2bf(v);
    }
    __syncthreads();
    for (int i = tid; i < 512; i += 256) {
        int pl = i >> 3, part = i & 7;
        uint4 v = *(const uint4*)&T[pl * 72 + part * 8];
        *(uint4*)&xt[(size_t)(p0 + pl) * 1536 + c0 + part * 8] = v;
    }
}

// ---------------------------------------------------------------------------
// Weight fragment-pack: src [Cout][Cin][9] f32 ->
// dst[g][s][f][lane][8] bf16 (g = cout group of NB*16, s = k-step = cb*9+t,
// f = n-frag). Lane lm = cout offset, quad = k-part.
// ---------------------------------------------------------------------------
__global__ __launch_bounds__(256)
void wpack_k(const float* __restrict__ src, short* __restrict__ dst,
             int Cin, int Cout, int S, int NB, int total)
{
    int i = blockIdx.x * 256 + threadIdx.x;
    if (i >= total) return;
    int e = i & 7, lane = (i >> 3) & 63;
    int lm = lane & 15, quad = lane >> 4;
    int rest = i >> 9;
    int f = rest % NB;
    int s = (rest / NB) % S;
    int g = rest / (NB * S);
    int cout = g * (NB * 16) + f * 16 + lm;
    int cb = s / 9, t = s % 9;
    int ch = cb * 32 + quad * 8 + e;
    dst[i] = (cout < Cout) ? (short)f2bf(src[((size_t)cout * Cin + ch) * 9 + t]) : 0;
}

// ---------------------------------------------------------------------------
// Flipped implicit-GEMM 3x3 conv, MFMA bf16. Block 256 thr = 4 waves.
// M = pixels (4 rows x 64), N = 32 couts (fragment-packed weights from global,
// software-prefetched one tap ahead). LDS: halo 6x66x40 = 31.7 KB.
// ---------------------------------------------------------------------------
__global__ __launch_bounds__(256, 4)
void convf_k(const short* __restrict__ Xt, int CinStr,
             const short* __restrict__ Wp, int S, int chunks,
             short* __restrict__ Out, int Cstr, int splitStride)
{
    __shared__ __align__(16) short sH[6 * 66 * 40];   // 31.7 KB
    const int tid = threadIdx.x, lane = tid & 63, wv = tid >> 6;
    const int lm = lane & 15, quad = lane >> 4;
    const int r0 = blockIdx.x * 4;            // 4 pixel rows
    const int g  = blockIdx.y;                // cout group of 32
    const int cb0 = blockIdx.z * chunks;
    short* out = Out + (size_t)blockIdx.z * splitStride;

    f4v acc[4][2];
#pragma unroll
    for (int ma = 0; ma < 4; ++ma)
#pragma unroll
        for (int nb = 0; nb < 2; ++nb)
#pragma unroll
            for (int r = 0; r < 4; ++r) acc[ma][nb][r] = 0.f;

    for (int cc = 0; cc < chunks; ++cc) {
        const int cb = cb0 + cc;
        const short* wpB = Wp + ((size_t)(g * S + cb * 9) * 2) * 512 + lane * 8;
        // prefetch tap-0 weight frags (overlaps halo staging + barrier)
        s8v bb[2];
        bb[0] = *(const s8v*)&wpB[0];
        bb[1] = *(const s8v*)&wpB[512];

        // ---- stage halo: 6 rows x 66 px x 32 ch (zero-padded) ----
        for (int i = tid; i < 1584; i += 256) {
            int slot = i >> 2, part = i & 3;
            int hr = slot / 66, px = slot % 66;
            int gy = r0 - 1 + hr, gx = px - 1;
            uint4 v = {0, 0, 0, 0};
            if (gy >= 0 && gy < 64 && gx >= 0 && gx < 64)
                v = *(const uint4*)&Xt[(size_t)(gy * 64 + gx) * CinStr + cb * 32 + part * 8];
            *(uint4*)&sH[slot * 40 + part * 8] = v;
        }
        __syncthreads();

#pragma unroll
        for (int t = 0; t < 9; ++t) {
            const int ty = t / 3, tx = t % 3;
            // prefetch next tap's weight frags (t=8 overreads 1KB into the
            // adjacent carved region -- allocated, discarded)
            s8v nb0 = *(const s8v*)&wpB[(size_t)((t + 1) * 2 + 0) * 512];
            s8v nb1 = *(const s8v*)&wpB[(size_t)((t + 1) * 2 + 1) * 512];
            s8v a[4];
#pragma unroll
            for (int ma = 0; ma < 4; ++ma)
                a[ma] = *(const s8v*)&sH[((wv + ty) * 66 + ma * 16 + lm + tx) * 40 + quad * 8];
#pragma unroll
            for (int ma = 0; ma < 4; ++ma) {
                acc[ma][0] = __builtin_amdgcn_mfma_f32_16x16x32_bf16(a[ma], bb[0], acc[ma][0], 0, 0, 0);
                acc[ma][1] = __builtin_amdgcn_mfma_f32_16x16x32_bf16(a[ma], bb[1], acc[ma][1], 0, 0, 0);
            }
            bb[0] = nb0; bb[1] = nb1;
        }
        __syncthreads();
    }

    const int py = (r0 + wv) * 64;
#pragma unroll
    for (int ma = 0; ma < 4; ++ma)
#pragma unroll
        for (int nb = 0; nb < 2; ++nb)
#pragma unroll
            for (int r = 0; r < 4; ++r)
                out[(size_t)(py + ma * 16 + quad * 4 + r) * Cstr + g * 32 + nb * 16 + lm]
                    = (short)f2bf(acc[ma][nb][r]);
}

// ---------------------------------------------------------------------------
// Sum bf16 K-split partials, optional relu, -> bf16
// ---------------------------------------------------------------------------
__global__ __launch_bounds__(256)
void ep_sumb_k(const short* __restrict__ P, short* __restrict__ outb,
               int nsplit, size_t splitStride, int n8, int relu)
{
    int i = blockIdx.x * 256 + threadIdx.x;
    if (i >= n8) return;
    size_t base = (size_t)i * 8;
    float s[8];
#pragma unroll
    for (int j = 0; j < 8; ++j) s[j] = 0.f;
    for (int sp = 0; sp < nsplit; ++sp) {
        uint4 v = *(const uint4*)&P[sp * splitStride + base];
        s[0] += bf2f(v.x & 0xffffu); s[1] += bf2f(v.x >> 16);
        s[2] += bf2f(v.y & 0xffffu); s[3] += bf2f(v.y >> 16);
        s[4] += bf2f(v.z & 0xffffu); s[5] += bf2f(v.z >> 16);
        s[6] += bf2f(v.w & 0xffffu); s[7] += bf2f(v.w >> 16);
    }
    if (relu) {
#pragma unroll
        for (int j = 0; j < 8; ++j) s[j] = fmaxf(s[j], 0.f);
    }
    uint4 o;
    o.x = f2bf(s[0]) | ((unsigned)f2bf(s[1]) << 16);
    o.y = f2bf(s[2]) | ((unsigned)f2bf(s[3]) << 16);
    o.z = f2bf(s[4]) | ((unsigned)f2bf(s[5]) << 16);
    o.w = f2bf(s[6]) | ((unsigned)f2bf(s[7]) << 16);
    *(uint4*)&outb[base] = o;
}

// conv4 epilogue: partials bf16 [16][4096][32] -> offs f32 [18][4096]
__global__ __launch_bounds__(256)
void ep_offs_k(const short* __restrict__ P, float* __restrict__ offs)
{
    int i = blockIdx.x * 256 + threadIdx.x;
    if (i >= 18 * HWPX) return;
    int m = i >> 12, px = i & 4095;
    float s = 0.f;
    for (int sp = 0; sp < 16; ++sp)
        s += bf2f((unsigned short)P[((size_t)sp * HWPX + px) * 32 + m]);
    offs[i] = s;
}

// ---------------------------------------------------------------------------
// Bilinear sampling -> Smp in MFMA fragment-packed order:
// Smp[pg][s][ma][lane][8]. Grid (256 px-blocks, 4 g-quarters).
// ---------------------------------------------------------------------------
__global__ __launch_bounds__(256)
void sample_k(const short* __restrict__ xcat, const float* __restrict__ offs,
              short* __restrict__ Smp)
{
    __shared__ int   s_mi[9][16][4];
    __shared__ float s_mw[9][16][4];
    const int tid = threadIdx.x;
    const int p0  = blockIdx.x * 16;
    const int gb  = blockIdx.y * 24;   // 24 of 96 channel-groups

    if (tid < 144) {
        int t = tid / 16, p = tid % 16;
        int pxg = p0 + p;
        int r = pxg >> 6, x = pxg & 63;
        float dy = offs[(size_t)(2 * t)     * HWPX + pxg];
        float dx = offs[(size_t)(2 * t + 1) * HWPX + pxg];
        float py  = (float)(r - 1 + t / 3) + dy;
        float pxf = (float)(x - 1 + t % 3) + dx;
        py  = fminf(fmaxf(py,  -1e6f), 1e6f);
        pxf = fminf(fmaxf(pxf, -1e6f), 1e6f);
        float y0f = floorf(py), x0f = floorf(pxf);
        float wy1 = py - y0f, wx1 = pxf - x0f;
        float wy0 = 1.f - wy1, wx0 = 1.f - wx1;
        bool vy0 = (y0f >=  0.f) && (y0f <= 63.f);
        bool vy1 = (y0f >= -1.f) && (y0f <= 62.f);
        bool vx0 = (x0f >=  0.f) && (x0f <= 63.f);
        bool vx1 = (x0f >= -1.f) && (x0f <= 62.f);
        int y0 = (int)fminf(fmaxf(y0f,       0.f), 63.f);
        int y1 = (int)fminf(fmaxf(y0f + 1.f, 0.f), 63.f);
        int x0 = (int)fminf(fmaxf(x0f,       0.f), 63.f);
        int x1 = (int)fminf(fmaxf(x0f + 1.f, 0.f), 63.f);
        s_mi[t][p][0] = y0 * 64 + x0;  s_mw[t][p][0] = (vy0 && vx0) ? wy0 * wx0 : 0.f;
        s_mi[t][p][1] = y0 * 64 + x1;  s_mw[t][p][1] = (vy0 && vx1) ? wy0 * wx1 : 0.f;
        s_mi[t][p][2] = y1 * 64 + x0;  s_mw[t][p][2] = (vy1 && vx0) ? wy1 * wx0 : 0.f;
        s_mi[t][p][3] = y1 * 64 + x1;  s_mw[t][p][3] = (vy1 && vx1) ? wy1 * wx1 : 0.f;
    }
    __syncthreads();

    for (int i = tid; i < 16 * 9 * 24; i += 256) {
        int p = i / 216, rest = i % 216;
        int t = rest / 24, g = gb + rest % 24;
        float a[8];
#pragma unroll
        for (int j = 0; j < 8; ++j) a[j] = 0.f;
#pragma unroll
        for (int c = 0; c < 4; ++c) {
            float w = s_mw[t][p][c];
            const short* src = xcat + (size_t)s_mi[t][p][c] * 1536 + 768 + g * 8;
            uint4 v = *(const uint4*)src;
            a[0] += w * bf2f(v.x & 0xffffu); a[1] += w * bf2f(v.x >> 16);
            a[2] += w * bf2f(v.y & 0xffffu); a[3] += w * bf2f(v.y >> 16);
            a[4] += w * bf2f(v.z & 0xffffu); a[5] += w * bf2f(v.z >> 16);
            a[6] += w * bf2f(v.w & 0xffffu); a[7] += w * bf2f(v.w >> 16);
        }
        uint4 o;
        o.x = f2bf(a[0]) | ((unsigned)f2bf(a[1]) << 16);
        o.y = f2bf(a[2]) | ((unsigned)f2bf(a[3]) << 16);
        o.z = f2bf(a[4]) | ((unsigned)f2bf(a[5]) << 16);
        o.w = f2bf(a[6]) | ((unsigned)f2bf(a[7]) << 16);
        int px = p0 + p;
        int pg = px >> 6, ma = (px >> 4) & 3, lmx = px & 15;
        int cb = g >> 2, qd = g & 3;
        size_t addr = ((((size_t)pg * 216 + cb * 9 + t) * 4 + ma) * 64 + qd * 16 + lmx) * 8;
        *(uint4*)&Smp[addr] = o;
    }
}

// ---------------------------------------------------------------------------
// Deform GEMM, zero-LDS, register-double-buffered (2-deep K pipeline).
// Grid (32 n, 6 m, 4 ksplit): n fastest => m-blocks sharing an Smp n-tile
// land on one XCD => B L2-resident. Prefetch step s+1 while MFMA'ing step s;
// final prefetch overreads one step into adjacent carved regions (allocated).
// ---------------------------------------------------------------------------
__global__ __launch_bounds__(256, 3)
void dgemm_k(const short* __restrict__ Ap, const short* __restrict__ Bp,
             short* __restrict__ P)
{
    const int tid = threadIdx.x, lane = tid & 63, wv = tid >> 6;
    const int lm = lane & 15, quad = lane >> 4;
    const int mg = blockIdx.y * 2 + (wv >> 1);    // 64-cout group 0..11
    const int pg = blockIdx.x * 2 + (wv & 1);     // 64-px group 0..63
    const int s0 = blockIdx.z * 54;
    const short* ap = Ap + (((size_t)mg * 216 + s0) * 4 * 64 + lane) * 8;
    const short* bp = Bp + (((size_t)pg * 216 + s0) * 4 * 64 + lane) * 8;

    f4v acc[4][4];
#pragma unroll
    for (int ma = 0; ma < 4; ++ma)
#pragma unroll
        for (int nb = 0; nb < 4; ++nb)
#pragma unroll
            for (int r = 0; r < 4; ++r) acc[ma][nb][r] = 0.f;

    s8v a0[4], b0[4], a1[4], b1[4];
#pragma unroll
    for (int f = 0; f < 4; ++f) {
        a0[f] = *(const s8v*)&ap[(size_t)f * 512];
        b0[f] = *(const s8v*)&bp[(size_t)f * 512];
    }

    for (int s = 0; s < 54; s += 2) {
#pragma unroll
        for (int f = 0; f < 4; ++f) {
            a1[f] = *(const s8v*)&ap[(size_t)((s + 1) * 4 + f) * 512];
            b1[f] = *(const s8v*)&bp[(size_t)((s + 1) * 4 + f) * 512];
        }
#pragma unroll
        for (int ma = 0; ma < 4; ++ma)
#pragma unroll
            for (int nb = 0; nb < 4; ++nb)
                acc[ma][nb] = __builtin_amdgcn_mfma_f32_16x16x32_bf16(
                    a0[ma], b0[nb], acc[ma][nb], 0, 0, 0);
#pragma unroll
        for (int f = 0; f < 4; ++f) {
            a0[f] = *(const s8v*)&ap[(size_t)((s + 2) * 4 + f) * 512];
            b0[f] = *(const s8v*)&bp[(size_t)((s + 2) * 4 + f) * 512];
        }
#pragma unroll
        for (int ma = 0; ma < 4; ++ma)
#pragma unroll
            for (int nb = 0; nb < 4; ++nb)
                acc[ma][nb] = __builtin_amdgcn_mfma_f32_16x16x32_bf16(
                    a1[ma], b1[nb], acc[ma][nb], 0, 0, 0);
    }

    short* p = P + (size_t)blockIdx.z * 768 * HWPX;
#pragma unroll
    for (int ma = 0; ma < 4; ++ma)
#pragma unroll
        for (int nb = 0; nb < 4; ++nb)
#pragma unroll
            for (int r = 0; r < 4; ++r)
                p[(size_t)(mg * 64 + ma * 16 + quad * 4 + r) * HWPX
                  + pg * 64 + nb * 16 + lm] = (short)f2bf(acc[ma][nb][r]);
}

// out f32 = sum of 4 bf16 partials
__global__ __launch_bounds__(256)
void ep_dg_k(const short* __restrict__ P, float* __restrict__ out)
{
    int i = blockIdx.x * 256 + threadIdx.x;
    if (i >= 768 * HWPX / 8) return;
    size_t base = (size_t)i * 8;
    float s[8];
#pragma unroll
    for (int j = 0; j < 8; ++j) s[j] = 0.f;
    for (int sp = 0; sp < 4; ++sp) {
        uint4 v = *(const uint4*)&P[(size_t)sp * 768 * HWPX + base];
        s[0] += bf2f(v.x & 0xffffu); s[1] += bf2f(v.x >> 16);
        s[2] += bf2f(v.y & 0xffffu); s[3] += bf2f(v.y >> 16);
        s[4] += bf2f(v.z & 0xffffu); s[5] += bf2f(v.z >> 16);
        s[6] += bf2f(v.w & 0xffffu); s[7] += bf2f(v.w >> 16);
    }
    float4 o0 = make_float4(s[0], s[1], s[2], s[3]);
    float4 o1 = make_float4(s[4], s[5], s[6], s[7]);
    *(float4*)&out[base]     = o0;
    *(float4*)&out[base + 4] = o1;
}

// ---------------------------------------------------------------------------
extern "C" void kernel_launch(void* const* d_in, const int* in_sizes, int n_in,
                              void* d_out, int out_size, void* d_ws, size_t ws_size,
                              hipStream_t stream)
{
    const float* x_in  = (const float*)d_in[0];
    const float* x_ref = (const float*)d_in[1];
    const float* w1    = (const float*)d_in[2];
    const float* w2    = (const float*)d_in[3];
    const float* w3    = (const float*)d_in[4];
    const float* ow    = (const float*)d_in[5];
    const float* dw    = (const float*)d_in[6];
    float* out = (float*)d_out;

    char* w = (char*)d_ws;
    size_t off = 0;
    auto carve = [&](size_t bytes) {
        void* p = w + off;
        off += (bytes + 255) & ~(size_t)255;
        return p;
    };
    short* xcat = (short*)carve((size_t)4096 * 1536 * 2);        // 12.58 MB
    short* w1p  = (short*)carve((size_t)6 * 432 * 2 * 512 * 2);  //  5.31 MB
    short* w2p  = (short*)carve((size_t)6 * 54 * 2 * 512 * 2);   //  0.66 MB
    short* w3p  = (short*)carve((size_t)48 * 54 * 2 * 512 * 2);  //  5.31 MB
    short* w4p  = (short*)carve((size_t)1 * 432 * 2 * 512 * 2);  //  0.88 MB
    short* dwp  = (short*)carve((size_t)12 * 216 * 4 * 512 * 2); // 10.62 MB
    float* offs = (float*)carve((size_t)18 * 4096 * 4);          //  0.29 MB
    short* Smp  = (short*)carve((size_t)4096 * 6912 * 2);        // 56.62 MB (packed)
    // REGION R: 25.17 MB, aliased across phases
    char*  R    = (char*)carve((size_t)2 * 768 * 4096 * 4);
    short* rh1  = (short*)R;                    // [4096][192] bf16
    short* rh2  = (short*)(R + 1572864);        // [4096][192] bf16
    short* Pb   = (short*)(R + 3145728);        // conv1 partials [12][4096][192]
    short* est  = (short*)(R + 3145728);        // [4096][1536] bf16
    short* Pb4  = (short*)(R + 15728640);       // conv4 partials [16][4096][32]
    short* Pdg  = (short*)R;                    // dgemm partials [4][768][4096] bf16

    tr_cat_k<<<dim3(24, 64), 256, 0, stream>>>(x_in, x_ref, xcat);
    // fragment-packed weights
    {
        int t1 = 6 * 432 * 2 * 512;
        wpack_k<<<(t1 + 255) / 256, 256, 0, stream>>>(w1, w1p, 1536, 192, 432, 2, t1);
        int t2 = 6 * 54 * 2 * 512;
        wpack_k<<<(t2 + 255) / 256, 256, 0, stream>>>(w2, w2p, 192, 192, 54, 2, t2);
        int t3 = 48 * 54 * 2 * 512;
        wpack_k<<<(t3 + 255) / 256, 256, 0, stream>>>(w3, w3p, 192, 1536, 54, 2, t3);
        int t4 = 1 * 432 * 2 * 512;
        wpack_k<<<(t4 + 255) / 256, 256, 0, stream>>>(ow, w4p, 1536, 18, 432, 2, t4);
        int t5 = 12 * 216 * 4 * 512;
        wpack_k<<<(t5 + 255) / 256, 256, 0, stream>>>(dw, dwp, 768, 768, 216, 4, t5);
    }

    const int n8 = 4096 * 192 / 8;
    // conv1: 1536->192 relu; ksplit 12 x 4 chunks; bf16 partials
    convf_k<<<dim3(16, 6, 12), 256, 0, stream>>>(xcat, 1536, w1p, 432, 4,
                                                 Pb, 192, 4096 * 192);
    ep_sumb_k<<<(n8 + 255) / 256, 256, 0, stream>>>(Pb, rh1, 12, (size_t)4096 * 192, n8, 1);
    // conv2: 192->192 relu; ksplit 6 x 1 chunk
    convf_k<<<dim3(16, 6, 6), 256, 0, stream>>>(rh1, 192, w2p, 54, 1,
                                                Pb, 192, 4096 * 192);
    ep_sumb_k<<<(n8 + 255) / 256, 256, 0, stream>>>(Pb, rh2, 6, (size_t)4096 * 192, n8, 1);
    // conv3: 192->1536, no split, direct bf16
    convf_k<<<dim3(16, 48, 1), 256, 0, stream>>>(rh2, 192, w3p, 54, 6,
                                                 est, 1536, 0);
    // conv4: 1536->18(pad 32); ksplit 16 x 3 chunks
    convf_k<<<dim3(16, 1, 16), 256, 0, stream>>>(est, 1536, w4p, 432, 3,
                                                 Pb4, 32, 4096 * 32);
    ep_offs_k<<<(18 * HWPX + 255) / 256, 256, 0, stream>>>(Pb4, offs);
    // deformable conv: fragment-packed sampling (4 g-quarters), zero-LDS GEMM
    sample_k<<<dim3(256, 4), 256, 0, stream>>>(xcat, offs, Smp);
    dgemm_k<<<dim3(32, 6, 4), 256, 0, stream>>>(dwp, Smp, Pdg);
    ep_dg_k<<<(768 * HWPX / 8 + 255) / 256, 256, 0, stream>>>(Pdg, out);
}

// Round 8
// 353.478 us; speedup vs baseline: 16.0593x; 1.0056x over previous
//
#include <hip/hip_runtime.h>

#define HWPX 4096   // 64*64 pixels

typedef short s8v  __attribute__((ext_vector_type(8)));   // 8 x bf16 (4 VGPR)
typedef float f4v  __attribute__((ext_vector_type(4)));   // 4 x f32  (MFMA C/D)

__device__ inline unsigned short f2bf(float f) {          // RNE f32 -> bf16
    unsigned u = __float_as_uint(f);
    return (unsigned short)((u + 0x7fffu + ((u >> 16) & 1u)) >> 16);
}
__device__ inline float bf2f(unsigned s) {
    return __uint_as_float(s << 16);
}

// ---------------------------------------------------------------------------
// Transpose+concat+cast: x_in/x_ref [768][4096] f32 -> xcat [4096 px][1536 ch] bf16
// ---------------------------------------------------------------------------
__global__ __launch_bounds__(256)
void tr_cat_k(const float* __restrict__ xa, const float* __restrict__ xb,
              short* __restrict__ xt)
{
    __shared__ __align__(16) short T[64 * 72];
    const int c0 = blockIdx.x * 64, p0 = blockIdx.y * 64, tid = threadIdx.x;
    for (int i = tid; i < 4096; i += 256) {
        int cl = i >> 6, pl = i & 63;
        int c = c0 + cl;
        float v = (c < 768) ? xa[(size_t)c * HWPX + p0 + pl]
                            : xb[(size_t)(c - 768) * HWPX + p0 + pl];
        T[pl * 72 + cl] = (short)f2bf(v);
    }
    __syncthreads();
    for (int i = tid; i < 512; i += 256) {
        int pl = i >> 3, part = i & 7;
        uint4 v = *(const uint4*)&T[pl * 72 + part * 8];
        *(uint4*)&xt[(size_t)(p0 + pl) * 1536 + c0 + part * 8] = v;
    }
}

// ---------------------------------------------------------------------------
// Fused weight fragment-pack for all 5 weights.
// dst[g][s][f][lane][8] bf16; s = cb*9+t; lane: lm=cout, quad=k-part.
// ---------------------------------------------------------------------------
__device__ inline void wpack1(const float* __restrict__ src, short* __restrict__ dst,
                              int i, int Cin, int Cout, int S, int NB)
{
    int e = i & 7, lane = (i >> 3) & 63;
    int lm = lane & 15, quad = lane >> 4;
    int rest = i >> 9;
    int f = rest % NB;
    int s = (rest / NB) % S;
    int g = rest / (NB * S);
    int cout = g * (NB * 16) + f * 16 + lm;
    int cb = s / 9, t = s % 9;
    int ch = cb * 32 + quad * 8 + e;
    dst[i] = (cout < Cout) ? (short)f2bf(src[((size_t)cout * Cin + ch) * 9 + t]) : 0;
}

#define C1 2654208   // w1: 3g*432s*4f*512
#define C2 2985984   // + w2: 3*54*4*512
#define C3 5640192   // + w3: 24*54*4*512
#define C4 6082560   // + w4: 1*432*2*512
#define C5 11390976  // + dw: 12*216*4*512

__global__ __launch_bounds__(256)
void wpack_all_k(const float* __restrict__ s1, const float* __restrict__ s2,
                 const float* __restrict__ s3, const float* __restrict__ s4,
                 const float* __restrict__ s5,
                 short* __restrict__ d1, short* __restrict__ d2,
                 short* __restrict__ d3, short* __restrict__ d4,
                 short* __restrict__ d5)
{
    int i = blockIdx.x * 256 + threadIdx.x;
    if (i < C1)      wpack1(s1, d1, i,      1536, 192,  432, 4);
    else if (i < C2) wpack1(s2, d2, i - C1, 192,  192,  54,  4);
    else if (i < C3) wpack1(s3, d3, i - C2, 192,  1536, 54,  4);
    else if (i < C4) wpack1(s4, d4, i - C3, 1536, 18,   432, 2);
    else if (i < C5) wpack1(s5, d5, i - C4, 768,  768,  216, 4);
}

// ---------------------------------------------------------------------------
// Flipped implicit-GEMM 3x3 conv, MFMA bf16. Block 256 thr = 4 waves.
// M = pixels (4 rows x 64), N = NB*16 couts (fragment-packed weights from
// global, prefetched one tap ahead). LDS: halo 6x66x40 = 31.7 KB.
// ---------------------------------------------------------------------------
template<int NB>
__global__ __launch_bounds__(256, 3)
void convf_k(const short* __restrict__ Xt, int CinStr,
             const short* __restrict__ Wp, int S, int chunks,
             short* __restrict__ Out, int Cstr, int splitStride)
{
    __shared__ __align__(16) short sH[6 * 66 * 40];   // 31.7 KB
    const int tid = threadIdx.x, lane = tid & 63, wv = tid >> 6;
    const int lm = lane & 15, quad = lane >> 4;
    const int r0 = blockIdx.x * 4;            // 4 pixel rows
    const int g  = blockIdx.y;                // cout group of NB*16
    const int cb0 = blockIdx.z * chunks;
    short* out = Out + (size_t)blockIdx.z * splitStride;

    f4v acc[4][NB];
#pragma unroll
    for (int ma = 0; ma < 4; ++ma)
#pragma unroll
        for (int nb = 0; nb < NB; ++nb)
#pragma unroll
            for (int r = 0; r < 4; ++r) acc[ma][nb][r] = 0.f;

    for (int cc = 0; cc < chunks; ++cc) {
        const int cb = cb0 + cc;
        const short* wpB = Wp + ((size_t)(g * S + cb * 9) * NB) * 512 + lane * 8;
        // prefetch tap-0 weight frags (overlaps halo staging + barrier)
        s8v bb[NB];
#pragma unroll
        for (int f = 0; f < NB; ++f)
            bb[f] = *(const s8v*)&wpB[(size_t)f * 512];

        // ---- stage halo: 6 rows x 66 px x 32 ch (zero-padded) ----
        for (int i = tid; i < 1584; i += 256) {
            int slot = i >> 2, part = i & 3;
            int hr = slot / 66, px = slot % 66;
            int gy = r0 - 1 + hr, gx = px - 1;
            uint4 v = {0, 0, 0, 0};
            if (gy >= 0 && gy < 64 && gx >= 0 && gx < 64)
                v = *(const uint4*)&Xt[(size_t)(gy * 64 + gx) * CinStr + cb * 32 + part * 8];
            *(uint4*)&sH[slot * 40 + part * 8] = v;
        }
        __syncthreads();

#pragma unroll
        for (int t = 0; t < 9; ++t) {
            const int ty = t / 3, tx = t % 3;
            // prefetch next tap (t=8 overreads into the next carved region)
            s8v nxt[NB];
#pragma unroll
            for (int f = 0; f < NB; ++f)
                nxt[f] = *(const s8v*)&wpB[(size_t)((t + 1) * NB + f) * 512];
            s8v a[4];
#pragma unroll
            for (int ma = 0; ma < 4; ++ma)
                a[ma] = *(const s8v*)&sH[((wv + ty) * 66 + ma * 16 + lm + tx) * 40 + quad * 8];
#pragma unroll
            for (int ma = 0; ma < 4; ++ma)
#pragma unroll
                for (int nb = 0; nb < NB; ++nb)
                    acc[ma][nb] = __builtin_amdgcn_mfma_f32_16x16x32_bf16(
                        a[ma], bb[nb], acc[ma][nb], 0, 0, 0);
#pragma unroll
            for (int f = 0; f < NB; ++f) bb[f] = nxt[f];
        }
        __syncthreads();
    }

    const int py = (r0 + wv) * 64;
#pragma unroll
    for (int ma = 0; ma < 4; ++ma)
#pragma unroll
        for (int nb = 0; nb < NB; ++nb)
#pragma unroll
            for (int r = 0; r < 4; ++r)
                out[(size_t)(py + ma * 16 + quad * 4 + r) * Cstr
                    + g * (NB * 16) + nb * 16 + lm] = (short)f2bf(acc[ma][nb][r]);
}

// ---------------------------------------------------------------------------
// Sum bf16 K-split partials, optional relu, -> bf16
// ---------------------------------------------------------------------------
__global__ __launch_bounds__(256)
void ep_sumb_k(const short* __restrict__ P, short* __restrict__ outb,
               int nsplit, size_t splitStride, int n8, int relu)
{
    int i = blockIdx.x * 256 + threadIdx.x;
    if (i >= n8) return;
    size_t base = (size_t)i * 8;
    float s[8];
#pragma unroll
    for (int j = 0; j < 8; ++j) s[j] = 0.f;
    for (int sp = 0; sp < nsplit; ++sp) {
        uint4 v = *(const uint4*)&P[sp * splitStride + base];
        s[0] += bf2f(v.x & 0xffffu); s[1] += bf2f(v.x >> 16);
        s[2] += bf2f(v.y & 0xffffu); s[3] += bf2f(v.y >> 16);
        s[4] += bf2f(v.z & 0xffffu); s[5] += bf2f(v.z >> 16);
        s[6] += bf2f(v.w & 0xffffu); s[7] += bf2f(v.w >> 16);
    }
    if (relu) {
#pragma unroll
        for (int j = 0; j < 8; ++j) s[j] = fmaxf(s[j], 0.f);
    }
    uint4 o;
    o.x = f2bf(s[0]) | ((unsigned)f2bf(s[1]) << 16);
    o.y = f2bf(s[2]) | ((unsigned)f2bf(s[3]) << 16);
    o.z = f2bf(s[4]) | ((unsigned)f2bf(s[5]) << 16);
    o.w = f2bf(s[6]) | ((unsigned)f2bf(s[7]) << 16);
    *(uint4*)&outb[base] = o;
}

// conv4 epilogue: partials bf16 [nsplit][4096][32] -> offs f32 [18][4096]
__global__ __launch_bounds__(256)
void ep_offs_k(const short* __restrict__ P, float* __restrict__ offs, int nsplit)
{
    int i = blockIdx.x * 256 + threadIdx.x;
    if (i >= 18 * HWPX) return;
    int m = i >> 12, px = i & 4095;
    float s = 0.f;
    for (int sp = 0; sp < nsplit; ++sp)
        s += bf2f((unsigned short)P[((size_t)sp * HWPX + px) * 32 + m]);
    offs[i] = s;
}

// ---------------------------------------------------------------------------
// Bilinear sampling -> Smp in MFMA fragment-packed order:
// Smp[pg][s][ma][lane][8]. Grid (256 px-blocks, 4 g-quarters).
// ---------------------------------------------------------------------------
__global__ __launch_bounds__(256)
void sample_k(const short* __restrict__ xcat, const float* __restrict__ offs,
              short* __restrict__ Smp)
{
    __shared__ int   s_mi[9][16][4];
    __shared__ float s_mw[9][16][4];
    const int tid = threadIdx.x;
    const int p0  = blockIdx.x * 16;
    const int gb  = blockIdx.y * 24;   // 24 of 96 channel-groups

    if (tid < 144) {
        int t = tid / 16, p = tid % 16;
        int pxg = p0 + p;
        int r = pxg >> 6, x = pxg & 63;
        float dy = offs[(size_t)(2 * t)     * HWPX + pxg];
        float dx = offs[(size_t)(2 * t + 1) * HWPX + pxg];
        float py  = (float)(r - 1 + t / 3) + dy;
        float pxf = (float)(x - 1 + t % 3) + dx;
        py  = fminf(fmaxf(py,  -1e6f), 1e6f);
        pxf = fminf(fmaxf(pxf, -1e6f), 1e6f);
        float y0f = floorf(py), x0f = floorf(pxf);
        float wy1 = py - y0f, wx1 = pxf - x0f;
        float wy0 = 1.f - wy1, wx0 = 1.f - wx1;
        bool vy0 = (y0f >=  0.f) && (y0f <= 63.f);
        bool vy1 = (y0f >= -1.f) && (y0f <= 62.f);
        bool vx0 = (x0f >=  0.f) && (x0f <= 63.f);
        bool vx1 = (x0f >= -1.f) && (x0f <= 62.f);
        int y0 = (int)fminf(fmaxf(y0f,       0.f), 63.f);
        int y1 = (int)fminf(fmaxf(y0f + 1.f, 0.f), 63.f);
        int x0 = (int)fminf(fmaxf(x0f,       0.f), 63.f);
        int x1 = (int)fminf(fmaxf(x0f + 1.f, 0.f), 63.f);
        s_mi[t][p][0] = y0 * 64 + x0;  s_mw[t][p][0] = (vy0 && vx0) ? wy0 * wx0 : 0.f;
        s_mi[t][p][1] = y0 * 64 + x1;  s_mw[t][p][1] = (vy0 && vx1) ? wy0 * wx1 : 0.f;
        s_mi[t][p][2] = y1 * 64 + x0;  s_mw[t][p][2] = (vy1 && vx0) ? wy1 * wx0 : 0.f;
        s_mi[t][p][3] = y1 * 64 + x1;  s_mw[t][p][3] = (vy1 && vx1) ? wy1 * wx1 : 0.f;
    }
    __syncthreads();

    for (int i = tid; i < 16 * 9 * 24; i += 256) {
        int p = i / 216, rest = i % 216;
        int t = rest / 24, g = gb + rest % 24;
        float a[8];
#pragma unroll
        for (int j = 0; j < 8; ++j) a[j] = 0.f;
#pragma unroll
        for (int c = 0; c < 4; ++c) {
            float w = s_mw[t][p][c];
            const short* src = xcat + (size_t)s_mi[t][p][c] * 1536 + 768 + g * 8;
            uint4 v = *(const uint4*)src;
            a[0] += w * bf2f(v.x & 0xffffu); a[1] += w * bf2f(v.x >> 16);
            a[2] += w * bf2f(v.y & 0xffffu); a[3] += w * bf2f(v.y >> 16);
            a[4] += w * bf2f(v.z & 0xffffu); a[5] += w * bf2f(v.z >> 16);
            a[6] += w * bf2f(v.w & 0xffffu); a[7] += w * bf2f(v.w >> 16);
        }
        uint4 o;
        o.x = f2bf(a[0]) | ((unsigned)f2bf(a[1]) << 16);
        o.y = f2bf(a[2]) | ((unsigned)f2bf(a[3]) << 16);
        o.z = f2bf(a[4]) | ((unsigned)f2bf(a[5]) << 16);
        o.w = f2bf(a[6]) | ((unsigned)f2bf(a[7]) << 16);
        int px = p0 + p;
        int pg = px >> 6, ma = (px >> 4) & 3, lmx = px & 15;
        int cb = g >> 2, qd = g & 3;
        size_t addr = ((((size_t)pg * 216 + cb * 9 + t) * 4 + ma) * 64 + qd * 16 + lmx) * 8;
        *(uint4*)&Smp[addr] = o;
    }
}

// ---------------------------------------------------------------------------
// Deform GEMM, zero-LDS, register-double-buffered (2-deep K pipeline).
// Grid (32 n, 6 m, 4 ksplit): n fastest => m-blocks sharing an Smp n-tile
// land on one XCD => B L2-resident.
// ---------------------------------------------------------------------------
__global__ __launch_bounds__(256, 3)
void dgemm_k(const short* __restrict__ Ap, const short* __restrict__ Bp,
             short* __restrict__ P)
{
    const int tid = threadIdx.x, lane = tid & 63, wv = tid >> 6;
    const int lm = lane & 15, quad = lane >> 4;
    const int mg = blockIdx.y * 2 + (wv >> 1);    // 64-cout group 0..11
    const int pg = blockIdx.x * 2 + (wv & 1);     // 64-px group 0..63
    const int s0 = blockIdx.z * 54;
    const short* ap = Ap + (((size_t)mg * 216 + s0) * 4 * 64 + lane) * 8;
    const short* bp = Bp + (((size_t)pg * 216 + s0) * 4 * 64 + lane) * 8;

    f4v acc[4][4];
#pragma unroll
    for (int ma = 0; ma < 4; ++ma)
#pragma unroll
        for (int nb = 0; nb < 4; ++nb)
#pragma unroll
            for (int r = 0; r < 4; ++r) acc[ma][nb][r] = 0.f;

    s8v a0[4], b0[4], a1[4], b1[4];
#pragma unroll
    for (int f = 0; f < 4; ++f) {
        a0[f] = *(const s8v*)&ap[(size_t)f * 512];
        b0[f] = *(const s8v*)&bp[(size_t)f * 512];
    }

    for (int s = 0; s < 54; s += 2) {
#pragma unroll
        for (int f = 0; f < 4; ++f) {
            a1[f] = *(const s8v*)&ap[(size_t)((s + 1) * 4 + f) * 512];
            b1[f] = *(const s8v*)&bp[(size_t)((s + 1) * 4 + f) * 512];
        }
#pragma unroll
        for (int ma = 0; ma < 4; ++ma)
#pragma unroll
            for (int nb = 0; nb < 4; ++nb)
                acc[ma][nb] = __builtin_amdgcn_mfma_f32_16x16x32_bf16(
                    a0[ma], b0[nb], acc[ma][nb], 0, 0, 0);
#pragma unroll
        for (int f = 0; f < 4; ++f) {
            a0[f] = *(const s8v*)&ap[(size_t)((s + 2) * 4 + f) * 512];
            b0[f] = *(const s8v*)&bp[(size_t)((s + 2) * 4 + f) * 512];
        }
#pragma unroll
        for (int ma = 0; ma < 4; ++ma)
#pragma unroll
            for (int nb = 0; nb < 4; ++nb)
                acc[ma][nb] = __builtin_amdgcn_mfma_f32_16x16x32_bf16(
                    a1[ma], b1[nb], acc[ma][nb], 0, 0, 0);
    }

    short* p = P + (size_t)blockIdx.z * 768 * HWPX;
#pragma unroll
    for (int ma = 0; ma < 4; ++ma)
#pragma unroll
        for (int nb = 0; nb < 4; ++nb)
#pragma unroll
            for (int r = 0; r < 4; ++r)
                p[(size_t)(mg * 64 + ma * 16 + quad * 4 + r) * HWPX
                  + pg * 64 + nb * 16 + lm] = (short)f2bf(acc[ma][nb][r]);
}

// out f32 = sum of 4 bf16 partials
__global__ __launch_bounds__(256)
void ep_dg_k(const short* __restrict__ P, float* __restrict__ out)
{
    int i = blockIdx.x * 256 + threadIdx.x;
    if (i >= 768 * HWPX / 8) return;
    size_t base = (size_t)i * 8;
    float s[8];
#pragma unroll
    for (int j = 0; j < 8; ++j) s[j] = 0.f;
    for (int sp = 0; sp < 4; ++sp) {
        uint4 v = *(const uint4*)&P[(size_t)sp * 768 * HWPX + base];
        s[0] += bf2f(v.x & 0xffffu); s[1] += bf2f(v.x >> 16);
        s[2] += bf2f(v.y & 0xffffu); s[3] += bf2f(v.y >> 16);
        s[4] += bf2f(v.z & 0xffffu); s[5] += bf2f(v.z >> 16);
        s[6] += bf2f(v.w & 0xffffu); s[7] += bf2f(v.w >> 16);
    }
    float4 o0 = make_float4(s[0], s[1], s[2], s[3]);
    float4 o1 = make_float4(s[4], s[5], s[6], s[7]);
    *(float4*)&out[base]     = o0;
    *(float4*)&out[base + 4] = o1;
}

// ---------------------------------------------------------------------------
extern "C" void kernel_launch(void* const* d_in, const int* in_sizes, int n_in,
                              void* d_out, int out_size, void* d_ws, size_t ws_size,
                              hipStream_t stream)
{
    const float* x_in  = (const float*)d_in[0];
    const float* x_ref = (const float*)d_in[1];
    const float* w1    = (const float*)d_in[2];
    const float* w2    = (const float*)d_in[3];
    const float* w3    = (const float*)d_in[4];
    const float* ow    = (const float*)d_in[5];
    const float* dw    = (const float*)d_in[6];
    float* out = (float*)d_out;

    char* w = (char*)d_ws;
    size_t off = 0;
    auto carve = [&](size_t bytes) {
        void* p = w + off;
        off += (bytes + 255) & ~(size_t)255;
        return p;
    };
    short* xcat = (short*)carve((size_t)4096 * 1536 * 2);        // 12.58 MB
    short* w1p  = (short*)carve((size_t)C1 * 2);                 //  5.31 MB (NB=4)
    short* w2p  = (short*)carve((size_t)(C2 - C1) * 2);          //  0.66 MB (NB=4)
    short* w3p  = (short*)carve((size_t)(C3 - C2) * 2);          //  5.31 MB (NB=4)
    short* w4p  = (short*)carve((size_t)(C4 - C3) * 2);          //  0.88 MB (NB=2)
    short* dwp  = (short*)carve((size_t)(C5 - C4) * 2);          // 10.62 MB (NB=4)
    float* offs = (float*)carve((size_t)18 * 4096 * 4);          //  0.29 MB
    short* Smp  = (short*)carve((size_t)4096 * 6912 * 2);        // 56.62 MB
    // REGION R: 25.17 MB, aliased across phases
    char*  R    = (char*)carve((size_t)2 * 768 * 4096 * 4);
    short* rh1  = (short*)R;                    // [4096][192] bf16
    short* rh2  = (short*)(R + 1572864);        // [4096][192] bf16
    short* est  = (short*)(R + 3145728);        // [4096][1536] bf16
    short* Pcv  = Smp;                          // conv partials (Smp idle til sample)
    short* Pdg  = (short*)R;                    // dgemm partials [4][768][4096] bf16

    tr_cat_k<<<dim3(24, 64), 256, 0, stream>>>(x_in, x_ref, xcat);
    wpack_all_k<<<(C5 + 255) / 256, 256, 0, stream>>>(w1, w2, w3, ow, dw,
                                                      w1p, w2p, w3p, w4p, dwp);

    const int n8 = 4096 * 192 / 8;
    // conv1: 1536->192 relu; N=64, ksplit 16 x 3 chunks; partials in Smp
    convf_k<4><<<dim3(16, 3, 16), 256, 0, stream>>>(xcat, 1536, w1p, 432, 3,
                                                    Pcv, 192, 4096 * 192);
    ep_sumb_k<<<(n8 + 255) / 256, 256, 0, stream>>>(Pcv, rh1, 16, (size_t)4096 * 192, n8, 1);
    // conv2: 192->192 relu; N=64, ksplit 6 x 1 chunk
    convf_k<4><<<dim3(16, 3, 6), 256, 0, stream>>>(rh1, 192, w2p, 54, 1,
                                                   Pcv, 192, 4096 * 192);
    ep_sumb_k<<<(n8 + 255) / 256, 256, 0, stream>>>(Pcv, rh2, 6, (size_t)4096 * 192, n8, 1);
    // conv3: 192->1536; N=64, ksplit 2 x 3 chunks; partials in Smp -> est
    convf_k<4><<<dim3(16, 24, 2), 256, 0, stream>>>(rh2, 192, w3p, 54, 3,
                                                    Pcv, 1536, 4096 * 1536);
    {
        const int n8c3 = 4096 * 1536 / 8;
        ep_sumb_k<<<(n8c3 + 255) / 256, 256, 0, stream>>>(Pcv, est, 2, (size_t)4096 * 1536, n8c3, 0);
    }
    // conv4: 1536->18(pad 32); N=32, ksplit 48 x 1 chunk; partials in Smp
    convf_k<2><<<dim3(16, 1, 48), 256, 0, stream>>>(est, 1536, w4p, 432, 1,
                                                    Pcv, 32, 4096 * 32);
    ep_offs_k<<<(18 * HWPX + 255) / 256, 256, 0, stream>>>(Pcv, offs, 48);
    // deformable conv: fragment-packed sampling (4 g-quarters), zero-LDS GEMM
    sample_k<<<dim3(256, 4), 256, 0, stream>>>(xcat, offs, Smp);
    dgemm_k<<<dim3(32, 6, 4), 256, 0, stream>>>(dwp, Smp, Pdg);
    ep_dg_k<<<(768 * HWPX / 8 + 255) / 256, 256, 0, stream>>>(Pdg, out);
}